// Round 12
// baseline (523.609 us; speedup 1.0000x reference)
//
#include <hip/hip_runtime.h>
#include <hip/hip_bf16.h>
#include <math.h>

#define S_  100
#define D_  30
#define T_  40
#define FT_ 512
#define FP_ 3
#define H_  64
#define G3  192
#define G4  256
#define M_  (D_*T_)   // 1200
#define NDY 6         // days per recur block

typedef __attribute__((ext_vector_type(8))) short short8_t;
typedef __attribute__((ext_vector_type(4))) float f32x4;

__device__ __forceinline__ float sigm(float x){ return 1.0f/(1.0f+__expf(-x)); }
__device__ __forceinline__ float tanhfast(float x){
  float e = __expf(2.0f*x);
  return 1.0f - 2.0f/(e + 1.0f);
}
__device__ __forceinline__ short f2bf(float f){
  unsigned u = __builtin_bit_cast(unsigned, f);
  u += 0x7FFFu + ((u>>16)&1u);
  return (short)(u>>16);
}
__device__ __forceinline__ float bf2f(unsigned short u){
  unsigned x = ((unsigned)u) << 16;
  return __builtin_bit_cast(float, x);
}
__device__ __forceinline__ short8_t pack8(float4 a, float4 b){
  short8_t o;
  o[0]=f2bf(a.x); o[1]=f2bf(a.y); o[2]=f2bf(a.z); o[3]=f2bf(a.w);
  o[4]=f2bf(b.x); o[5]=f2bf(b.y); o[6]=f2bf(b.z); o[7]=f2bf(b.w);
  return o;
}

// ---------------------------------------------------------------- K1: GX[s][m][gate] (bf16)
// 1 wave per 64x64 tile, NO barriers in main loop. 2-deep register pipeline:
// loads for panel k+2 issued while computing panel k. Direct fp32 loads.
#define LOADP(SET, KP)                                                        \
  {                                                                           \
    const int ko = (KP) * 32;                                                 \
    _Pragma("unroll")                                                         \
    for (int q = 0; q < 4; ++q) {                                             \
      SET##a[q][0] = *reinterpret_cast<const float4*>(aP[q] + ko);            \
      SET##a[q][1] = *reinterpret_cast<const float4*>(aP[q] + ko + 4);        \
      SET##b[q][0] = *reinterpret_cast<const float4*>(bP[q] + ko);            \
      SET##b[q][1] = *reinterpret_cast<const float4*>(bP[q] + ko + 4);        \
    }                                                                         \
  }

#define COMPP(SET, KP)                                                        \
  {                                                                           \
    short8_t afr[4], bfr[4];                                                  \
    _Pragma("unroll")                                                         \
    for (int q = 0; q < 4; ++q) {                                             \
      afr[q] = pack8(SET##a[q][0], SET##a[q][1]);                             \
      bfr[q] = pack8(SET##b[q][0], SET##b[q][1]);                             \
    }                                                                         \
    if ((KP) + 2 < 16) LOADP(SET, (KP) + 2)                                   \
    _Pragma("unroll")                                                         \
    for (int mt = 0; mt < 4; ++mt)                                            \
      _Pragma("unroll")                                                       \
      for (int nt = 0; nt < 4; ++nt)                                          \
        acc[mt][nt] = __builtin_amdgcn_mfma_f32_16x16x32_bf16(                \
            afr[mt], bfr[nt], acc[mt][nt], 0,0,0);                            \
  }

__global__ __launch_bounds__(64, 2) void k_gemm(
    const float* __restrict__ text, const float* __restrict__ Wall,
    const float* __restrict__ bW, const float* __restrict__ bU,
    unsigned short* __restrict__ GX)
{
  // bijective XCD swizzle (7600 = 8*950)
  const int orig = blockIdx.x;
  const int wg = (orig & 7) * 950 + (orig >> 3);
  const int s  = wg / 76;
  const int r76 = wg % 76;
  const int m0 = (r76 >> 2) * 64;
  const int n0 = (r76 & 3) * 64;
  const int lane = threadIdx.x;
  const int fr = lane & 15, hi = lane >> 4;

  __shared__ short Es[64][72];

  const float* Xs = text + (size_t)s * ((size_t)M_*FT_);
  const float* Ws = Wall + (size_t)s * ((size_t)G4*FT_);

  const float* aP[4];
  const float* bP[4];
  #pragma unroll
  for (int q = 0; q < 4; ++q) {
    int row = m0 + q*16 + fr; if (row > M_-1) row = M_-1;
    aP[q] = Xs + (size_t)row*FT_ + hi*8;
    bP[q] = Ws + (size_t)(n0 + q*16 + fr)*FT_ + hi*8;
  }
  float biasv[4];
  #pragma unroll
  for (int q = 0; q < 4; ++q)
    biasv[q] = bW[s*G4 + n0 + q*16 + fr] + bU[s*G4 + n0 + q*16 + fr];

  f32x4 acc[4][4];
  #pragma unroll
  for (int i=0;i<4;++i)
    #pragma unroll
    for (int j=0;j<4;++j) acc[i][j] = (f32x4)(0.f);

  float4 Xa[4][2], Xb[4][2], Ya[4][2], Yb[4][2];
  LOADP(X, 0)
  LOADP(Y, 1)

  #pragma unroll
  for (int kb = 0; kb < 16; kb += 2) {
    COMPP(X, kb)
    COMPP(Y, kb+1)
  }

  // epilogue: transpose through LDS, coalesced row stores
  #pragma unroll
  for (int mt = 0; mt < 4; ++mt)
    #pragma unroll
    for (int nt = 0; nt < 4; ++nt)
      #pragma unroll
      for (int rr = 0; rr < 4; ++rr)
        Es[mt*16 + hi*4 + rr][nt*16 + fr] = f2bf(acc[mt][nt][rr] + biasv[nt]);
  __syncthreads();
  {
    const int m = m0 + lane;
    if (m < M_) {
      unsigned short* dst = GX + ((size_t)s*M_ + m)*G4 + n0;
      #pragma unroll
      for (int j = 0; j < 4; ++j)
        *reinterpret_cast<short8_t*>(dst + j*8) =
            *reinterpret_cast<const short8_t*>(&Es[lane][j*8]);
    }
  }
}

// ---------------------------------------------------------------- K2: TimeLSTM (6 days/block) + day attn (blocks 0..499); price-GRU (500..599)
#define RECUR_STEP(T_CUR, GXU, GXP)                                           \
  {                                                                           \
    {                                                                         \
      const int tpf = ((T_CUR)+1 < T_) ? (T_CUR)+1 : (T_CUR);                 \
      const unsigned short* GXt = GX + ((size_t)s*M_ + d0*T_ + tpf)*G4;       \
      _Pragma("unroll")                                                       \
      for (int it = 0; it < 2; ++it) {                                        \
        int d = it*4 + wave;                                                  \
        if (d < NDY) {                                                        \
          const unsigned short* p = GXt + (size_t)d*T_*G4 + lane;             \
          GXP[it][0]=bf2f(p[0]);   GXP[it][1]=bf2f(p[64]);                    \
          GXP[it][2]=bf2f(p[128]); GXP[it][3]=bf2f(p[192]);                   \
        }                                                                     \
      }                                                                       \
    }                                                                         \
    f32x4 acc1_0=(f32x4)(0.f), acc1_1=(f32x4)(0.f);                           \
    f32x4 acc1_2=(f32x4)(0.f), acc1_3=(f32x4)(0.f);                           \
    f32x4 acc2=(f32x4)(0.f);                                                  \
    _Pragma("unroll")                                                         \
    for (int kw = 0; kw < 2; ++kw) {                                          \
      short8_t bfrag = *reinterpret_cast<const short8_t*>(&Hn[fr][kw*32+fk]); \
      acc1_0 = __builtin_amdgcn_mfma_f32_16x16x32_bf16(ureg[0][kw], bfrag, acc1_0,0,0,0); \
      acc1_1 = __builtin_amdgcn_mfma_f32_16x16x32_bf16(ureg[1][kw], bfrag, acc1_1,0,0,0); \
      acc1_2 = __builtin_amdgcn_mfma_f32_16x16x32_bf16(ureg[2][kw], bfrag, acc1_2,0,0,0); \
      acc1_3 = __builtin_amdgcn_mfma_f32_16x16x32_bf16(ureg[3][kw], bfrag, acc1_3,0,0,0); \
      short8_t cfrag = *reinterpret_cast<const short8_t*>(&Cn[fr][kw*32+fk]); \
      acc2 = __builtin_amdgcn_mfma_f32_16x16x32_bf16(wdreg[kw], cfrag, acc2,0,0,0); \
    }                                                                         \
    *reinterpret_cast<f32x4*>(&G1[l15][wave*64 +  0 + h4]) = acc1_0;          \
    *reinterpret_cast<f32x4*>(&G1[l15][wave*64 + 16 + h4]) = acc1_1;          \
    *reinterpret_cast<f32x4*>(&G1[l15][wave*64 + 32 + h4]) = acc1_2;          \
    *reinterpret_cast<f32x4*>(&G1[l15][wave*64 + 48 + h4]) = acc1_3;          \
    *reinterpret_cast<f32x4*>(&G2l[l15][wave*16 + h4]) = acc2;                \
    __syncthreads();                                                          \
    _Pragma("unroll")                                                         \
    for (int it = 0; it < 2; ++it) {                                          \
      int d = it*4 + wave;                                                    \
      if (d < NDY) {                                                          \
        float gf = G1[d][lane]       + GXU[it][0];                            \
        float gi = G1[d][64 + lane]  + GXU[it][1];                            \
        float go = G1[d][128 + lane] + GXU[it][2];                            \
        float gc = G1[d][192 + lane] + GXU[it][3];                            \
        float f  = sigm(gf), ig = sigm(gi), og = sigm(go), ct = sigm(gc);     \
        float cs1 = tanhfast(G2l[d][lane] + bdl[lane]);                       \
        float tvv = tsl[d][(T_CUR)];                                          \
        float c  = Cf[d][lane];                                               \
        float cadj = c - cs1 + cs1*tvv;                                       \
        float c2 = f*cadj + ig*ct;                                            \
        float h2 = og*tanhfast(c2);                                           \
        Cf[d][lane] = c2; Cn[d][lane] = f2bf(c2); Hn[d][lane] = f2bf(h2);     \
        outs_lds[d][(T_CUR)][lane] = f2bf(h2);                                \
      }                                                                       \
    }                                                                         \
    __syncthreads();                                                          \
  }

__global__ __launch_bounds__(256) void k_recur(
    const unsigned short* __restrict__ GX, const float* __restrict__ Uall,
    const float* __restrict__ Wd, const float* __restrict__ bd,
    const float* __restrict__ ts, const float* __restrict__ taW,
    const float* __restrict__ tab, float* __restrict__ news,
    const float* __restrict__ price, const float* __restrict__ pWih,
    const float* __restrict__ pWhh, const float* __restrict__ pbih,
    const float* __restrict__ pbhh, const float* __restrict__ paW,
    const float* __restrict__ pab, float* __restrict__ xvec)
{
  const int bid = blockIdx.x;
  const int tid = threadIdx.x;
  const int lane = tid & 63, wave = tid >> 6;

  __shared__ float G1[16][260];
  __shared__ float G2l[16][68];
  __shared__ float Cf[8][68];
  __shared__ short Hn[16][72];
  __shared__ short Cn[16][72];
  __shared__ float tsl[NDY][T_];
  __shared__ float bdl[H_], tabl[H_];
  __shared__ float scl[NDY][T_];
  __shared__ short outs_lds[NDY][T_][68];

  if (bid >= 5*S_) {
    // =================== price-GRU path ===================
    const int s = bid - 5*S_;
    float* base = &G1[0][0];
    float* hs   = base;                       // 64
    float (*outsb)[H_+1] = (float(*)[H_+1])(base + 64);   // 30 x 65
    float* gsum = base + 64 + D_*(H_+1);      // 128
    float* gxn  = gsum + 128;                 // 64
    float* ghn  = gxn + 64;                   // 64
    float (*pt)[H_] = (float(*)[H_])(ghn + 64);  // 4 x 64
    float* vs   = ghn + 64 + 4*H_;            // 64
    float* as_  = vs + 64;                    // 30
    const int row = lane, q = wave;

    float wih[3]; float whh[64]; float bihr=0.f, bhhr=0.f;
    if (tid < G3) {
      const float* wp = pWih + ((size_t)s*G3 + tid)*FP_;
      wih[0]=wp[0]; wih[1]=wp[1]; wih[2]=wp[2];
      const float* hp = pWhh + ((size_t)s*G3 + tid)*H_;
      #pragma unroll
      for (int j=0;j<64;++j) whh[j]=hp[j];
      bihr = pbih[s*G3+tid]; bhhr = pbhh[s*G3+tid];
    }
    if (tid < H_) hs[tid]=0.f;
    __syncthreads();

    for (int d=0; d<D_; ++d) {
      if (tid < G3) {
        const float* pp = price + ((size_t)s*D_ + d)*FP_;
        float p0=pp[0], p1=pp[1], p2=pp[2];
        float gx = bihr + wih[0]*p0 + wih[1]*p1 + wih[2]*p2;
        float gh = bhhr;
        const float4* h4p = reinterpret_cast<const float4*>(hs);
        #pragma unroll
        for (int j4=0;j4<16;++j4) {
          float4 hv=h4p[j4];
          gh = fmaf(whh[j4*4+0],hv.x,gh); gh = fmaf(whh[j4*4+1],hv.y,gh);
          gh = fmaf(whh[j4*4+2],hv.z,gh); gh = fmaf(whh[j4*4+3],hv.w,gh);
        }
        if (tid < 128) gsum[tid] = gx + gh;
        else { gxn[tid-128] = gx; ghn[tid-128] = gh; }
      }
      __syncthreads();
      if (tid < H_) {
        float r = sigm(gsum[tid]);
        float z = sigm(gsum[64+tid]);
        float n = tanhf(gxn[tid] + r*ghn[tid]);
        float h2 = (1.f-z)*n + z*hs[tid];
        hs[tid]=h2; outsb[d][tid]=h2;
      }
      __syncthreads();
    }
    {
      const float* Wp = paW + ((size_t)s*H_ + row)*H_ + q*16;
      float p = 0.f;
      #pragma unroll
      for (int j=0;j<16;++j) p = fmaf(Wp[j], hs[q*16+j], p);
      pt[q][row] = p;
    }
    __syncthreads();
    if (tid < H_) vs[tid] = pt[0][tid]+pt[1][tid]+pt[2][tid]+pt[3][tid] + pab[s*H_+tid];
    __syncthreads();
    if (tid < D_) {
      float sc = 0.f;
      for (int h=0;h<H_;++h) sc = fmaf(outsb[tid][h], vs[h], sc);
      as_[tid] = sc;
    }
    __syncthreads();
    if (tid == 0) {
      float m = -1e30f;
      for (int t=0;t<D_;++t) m = fmaxf(m, as_[t]);
      float sum = 0.f;
      for (int t=0;t<D_;++t) { float e = __expf(as_[t]-m); as_[t]=e; sum += e; }
      float inv = 1.0f/sum;
      for (int t=0;t<D_;++t) as_[t] *= inv;
    }
    __syncthreads();
    if (tid < H_) {
      float acc = 0.f;
      for (int t=0;t<D_;++t) acc = fmaf(as_[t], outsb[t][tid], acc);
      xvec[s*H_+tid] = acc;
    }
    return;
  }

  // =================== TimeLSTM path ===================
  const int s  = bid / 5;
  const int d0 = (bid % 5) * NDY;
  const int fr = lane & 15, fk = (lane >> 4) * 8;
  const int l15 = lane & 15, h4 = (lane >> 4) * 4;

  for (int e = tid; e < 16*72; e += 256) { (&Hn[0][0])[e] = 0; (&Cn[0][0])[e] = 0; }
  for (int e = tid; e < 8*68; e += 256) (&Cf[0][0])[e] = 0.f;
  for (int e = tid; e < NDY*T_; e += 256)
    (&tsl[0][0])[e] = ts[((size_t)s*D_ + d0)*T_ + e];
  if (tid < H_) { bdl[tid] = bd[s*H_ + tid]; tabl[tid] = tab[s*H_ + tid]; }

  short8_t ureg[4][2], wdreg[2], twreg[2];
  {
    const float* Uf  = Uall + (size_t)s*G4*H_;
    const float* Wdf = Wd   + (size_t)s*H_*H_;
    const float* Twf = taW  + (size_t)s*H_*H_;
    #pragma unroll
    for (int mt = 0; mt < 4; ++mt)
      #pragma unroll
      for (int kw = 0; kw < 2; ++kw) {
        const float* p = Uf + (size_t)(wave*64 + mt*16 + fr)*H_ + kw*32 + fk;
        ureg[mt][kw] = pack8(*reinterpret_cast<const float4*>(p),
                             *reinterpret_cast<const float4*>(p + 4));
      }
    #pragma unroll
    for (int kw = 0; kw < 2; ++kw) {
      const float* p = Wdf + (size_t)(wave*16 + fr)*H_ + kw*32 + fk;
      wdreg[kw] = pack8(*reinterpret_cast<const float4*>(p),
                        *reinterpret_cast<const float4*>(p + 4));
      const float* q = Twf + (size_t)(wave*16 + fr)*H_ + kw*32 + fk;
      twreg[kw] = pack8(*reinterpret_cast<const float4*>(q),
                        *reinterpret_cast<const float4*>(q + 4));
    }
  }
  __syncthreads();

  float gxA[2][4], gxB[2][4];
  {
    const unsigned short* GXt = GX + ((size_t)s*M_ + d0*T_)*G4;
    #pragma unroll
    for (int it = 0; it < 2; ++it) {
      int d = it*4 + wave;
      if (d < NDY) {
        const unsigned short* p = GXt + (size_t)d*T_*G4 + lane;
        gxA[it][0]=bf2f(p[0]);   gxA[it][1]=bf2f(p[64]);
        gxA[it][2]=bf2f(p[128]); gxA[it][3]=bf2f(p[192]);
      }
    }
  }

  for (int t = 0; t < T_; t += 2) {
    RECUR_STEP(t,   gxA, gxB)
    RECUR_STEP(t+1, gxB, gxA)
  }

  // ---- folded day attention ----
  {
    f32x4 accv = (f32x4)(0.f);
    #pragma unroll
    for (int kw = 0; kw < 2; ++kw) {
      short8_t hfr = *reinterpret_cast<const short8_t*>(&Hn[fr][kw*32+fk]);
      accv = __builtin_amdgcn_mfma_f32_16x16x32_bf16(twreg[kw], hfr, accv, 0,0,0);
    }
    *reinterpret_cast<f32x4*>(&G2l[l15][wave*16 + h4]) = accv;
  }
  __syncthreads();
  for (int e = tid; e < NDY*H_; e += 256) {
    int d = e >> 6, i = e & 63;
    G2l[d][i] += tabl[i];
  }
  __syncthreads();
  for (int idx = tid; idx < NDY*T_; idx += 256) {
    int d = idx / T_, t = idx % T_;
    float sc = 0.f;
    #pragma unroll 8
    for (int l = 0; l < H_; ++l)
      sc = fmaf(bf2f((unsigned short)outs_lds[d][t][l]), G2l[d][l], sc);
    scl[d][t] = sc;
  }
  __syncthreads();
  if (tid < NDY) {
    float m = -1e30f;
    for (int t = 0; t < T_; ++t) m = fmaxf(m, scl[tid][t]);
    float sum = 0.f;
    for (int t = 0; t < T_; ++t) { float e = __expf(scl[tid][t]-m); scl[tid][t]=e; sum+=e; }
    float inv = 1.f/sum;
    for (int t = 0; t < T_; ++t) scl[tid][t] *= inv;
  }
  __syncthreads();
  {
    const int l = tid & 63, w = tid >> 6;
    for (int d = w; d < NDY; d += 4) {
      float o = 0.f;
      #pragma unroll 8
      for (int t = 0; t < T_; ++t)
        o = fmaf(scl[d][t], bf2f((unsigned short)outs_lds[d][t][l]), o);
      news[((size_t)s*D_ + d0 + d)*H_ + l] = o;
    }
  }
}

// ---------------------------------------------------------------- K4: stock-GRU over news + attention -> tvec
__global__ __launch_bounds__(256) void k_rnn(
    const float* __restrict__ news, const float* __restrict__ sWih,
    const float* __restrict__ sWhh, const float* __restrict__ sbih,
    const float* __restrict__ sbhh, const float* __restrict__ saW,
    const float* __restrict__ sab, float* __restrict__ tvecg)
{
  const int s = blockIdx.x;
  const int tid = threadIdx.x;
  const int row = tid & 63, q = tid >> 6;
  __shared__ float xs[H_], hs[H_];
  __shared__ float outsb[D_][H_+1];
  __shared__ float gsum[128], gxn[64], ghn[64];
  __shared__ float pt[4][H_], vs[H_], as_[D_];

  float wih[64]; float whh[64]; float bihr=0.f, bhhr=0.f;
  if (tid < G3) {
    const float* wp = sWih + ((size_t)s*G3 + tid)*H_;
    const float* hp = sWhh + ((size_t)s*G3 + tid)*H_;
    #pragma unroll
    for (int j=0;j<64;++j) { wih[j]=wp[j]; whh[j]=hp[j]; }
    bihr = sbih[s*G3+tid]; bhhr = sbhh[s*G3+tid];
  }
  if (tid < H_) hs[tid]=0.f;
  __syncthreads();

  for (int d=0; d<D_; ++d) {
    if (tid < H_) xs[tid] = news[((size_t)s*D_ + d)*H_ + tid];
    __syncthreads();
    if (tid < G3) {
      float gx = bihr, gh = bhhr;
      const float4* x4 = reinterpret_cast<const float4*>(xs);
      const float4* h4p = reinterpret_cast<const float4*>(hs);
      #pragma unroll
      for (int j4=0;j4<16;++j4) {
        float4 xv=x4[j4]; float4 hv=h4p[j4];
        gx = fmaf(wih[j4*4+0],xv.x,gx); gx = fmaf(wih[j4*4+1],xv.y,gx);
        gx = fmaf(wih[j4*4+2],xv.z,gx); gx = fmaf(wih[j4*4+3],xv.w,gx);
        gh = fmaf(whh[j4*4+0],hv.x,gh); gh = fmaf(whh[j4*4+1],hv.y,gh);
        gh = fmaf(whh[j4*4+2],hv.z,gh); gh = fmaf(whh[j4*4+3],hv.w,gh);
      }
      if (tid < 128) gsum[tid] = gx + gh;
      else { gxn[tid-128] = gx; ghn[tid-128] = gh; }
    }
    __syncthreads();
    if (tid < H_) {
      float r = sigm(gsum[tid]);
      float z = sigm(gsum[64+tid]);
      float n = tanhf(gxn[tid] + r*ghn[tid]);
      float h2 = (1.f-z)*n + z*hs[tid];
      hs[tid]=h2; outsb[d][tid]=h2;
    }
    __syncthreads();
  }

  {
    const float* Wp = saW + ((size_t)s*H_ + row)*H_ + q*16;
    float p = 0.f;
    #pragma unroll
    for (int j=0;j<16;++j) p = fmaf(Wp[j], hs[q*16+j], p);
    pt[q][row] = p;
    __syncthreads();
    if (tid < H_) vs[tid] = pt[0][tid]+pt[1][tid]+pt[2][tid]+pt[3][tid] + sab[s*H_+tid];
    __syncthreads();
    if (tid < D_) {
      float sc = 0.f;
      for (int h=0;h<H_;++h) sc = fmaf(outsb[tid][h], vs[h], sc);
      as_[tid] = sc;
    }
    __syncthreads();
    if (tid == 0) {
      float m = -1e30f;
      for (int t=0;t<D_;++t) m = fmaxf(m, as_[t]);
      float sum = 0.f;
      for (int t=0;t<D_;++t) { float e = __expf(as_[t]-m); as_[t]=e; sum += e; }
      float inv = 1.0f/sum;
      for (int t=0;t<D_;++t) as_[t] *= inv;
    }
    __syncthreads();
    if (tid < H_) {
      float acc = 0.f;
      for (int t=0;t<D_;++t) acc = fmaf(as_[t], outsb[t][tid], acc);
      tvecg[s*H_+tid] = acc;
    }
  }
}

// ---------------------------------------------------------------- K5b: bilinear -> feat
__global__ __launch_bounds__(256) void k_bilin(
    const float* __restrict__ tvec, const float* __restrict__ xvec,
    const float* __restrict__ biW, const float* __restrict__ bib,
    float* __restrict__ feat)
{
  const int s = blockIdx.x >> 2;
  const int k0 = (blockIdx.x & 3) * 16;
  const int tid = threadIdx.x;
  const int lane = tid & 63, w = tid >> 6;
  __shared__ float pmat[H_*H_];
  __shared__ float tl[H_], xl[H_];
  if (tid < H_) { tl[tid] = tvec[s*H_+tid]; xl[tid] = xvec[s*H_+tid]; }
  __syncthreads();
  for (int e = tid; e < H_*H_; e += 256) pmat[e] = tl[e>>6]*xl[e&63];
  __syncthreads();
  const float4* P4 = reinterpret_cast<const float4*>(pmat);
  #pragma unroll
  for (int kk = 0; kk < 4; ++kk) {
    int k = k0 + kk*4 + w;
    const float4* W4 = reinterpret_cast<const float4*>(biW + ((size_t)s*H_ + k)*H_*H_);
    float acc = 0.f;
    #pragma unroll
    for (int r = 0; r < 16; ++r) {
      float4 wv = W4[r*64 + lane];
      float4 pv = P4[r*64 + lane];
      acc += wv.x*pv.x + wv.y*pv.y + wv.z*pv.z + wv.w*pv.w;
    }
    #pragma unroll
    for (int off = 32; off > 0; off >>= 1) acc += __shfl_down(acc, off, 64);
    if (lane == 0) feat[s*H_ + k] = tanhf(acc + bib[s*H_+k]);
  }
}

// ---------------------------------------------------------------- K6: head
__global__ __launch_bounds__(1024) void k_head(
    const float* __restrict__ feat, const float* __restrict__ blW,
    const float* __restrict__ blb, const float* __restrict__ Wq,
    const float* __restrict__ bq, const float* __restrict__ Wk,
    const float* __restrict__ bk, const float* __restrict__ fcW,
    const float* __restrict__ fcb, const int* __restrict__ label,
    float* __restrict__ Qg, float* __restrict__ Kg, float* __restrict__ scw,
    float* __restrict__ dout)
{
  const int tid = threadIdx.x;
  __shared__ float fs[S_*H_];
  __shared__ float mhs[S_*H_];
  __shared__ float o1[S_*2];
  __shared__ float lt[S_];

  for (int e=tid; e<S_*H_; e+=1024) fs[e] = feat[e];
  __syncthreads();

  if (tid < 2*S_) {
    int s = tid>>1, c = tid&1;
    const float* w = blW + ((size_t)(S_-1)*2 + c)*H_;
    float a = blb[(S_-1)*2 + c];
    for (int h=0;h<H_;++h) a = fmaf(fs[s*H_+h], w[h], a);
    o1[tid] = tanhf(a);
  }
  for (int e=tid; e<S_*H_; e+=1024) {
    int s = e>>6, o = e&63;
    float aq = bq[o], ak = bk[o];
    const float* wq = Wq + o*H_;
    const float* wk = Wk + o*H_;
    for (int h=0;h<H_;++h) { float f = fs[s*H_+h]; aq = fmaf(f, wq[h], aq); ak = fmaf(f, wk[h], ak); }
    Qg[e]=aq; Kg[e]=ak;
  }
  __syncthreads();

  if (tid < 4*S_) {
    int s = tid % S_, hd = tid / S_;
    const float* qr = Qg + s*H_ + hd*16;
    float m = -1e30f;
    for (int t=0;t<S_;++t) {
      const float* kr = Kg + t*H_ + hd*16;
      float sc=0.f;
      #pragma unroll
      for (int d2=0; d2<16; ++d2) sc = fmaf(qr[d2], kr[d2], sc);
      sc *= 0.25f;
      scw[(size_t)tid*S_+t]=sc;
      m = fmaxf(m, sc);
    }
    float sum=0.f;
    for (int t=0;t<S_;++t) { float e=__expf(scw[(size_t)tid*S_+t]-m); scw[(size_t)tid*S_+t]=e; sum+=e; }
    float inv=1.f/sum;
    float acc[16];
    #pragma unroll
    for (int d2=0;d2<16;++d2) acc[d2]=0.f;
    for (int t=0;t<S_;++t) {
      float a = scw[(size_t)tid*S_+t]*inv;
      #pragma unroll
      for (int d2=0;d2<16;++d2) acc[d2] = fmaf(a, fs[t*H_ + hd*16 + d2], acc[d2]);
    }
    #pragma unroll
    for (int d2=0;d2<16;++d2) mhs[s*H_ + hd*16 + d2] = acc[d2];
  }
  __syncthreads();

  if (tid < S_) {
    int s = tid;
    float e0 = fcb[0], e1 = fcb[1];
    for (int h=0;h<H_;++h) { float mv = mhs[s*H_+h]; e0 = fmaf(mv, fcW[h], e0); e1 = fmaf(mv, fcW[H_+h], e1); }
    float x0 = e0>0.f?e0:(__expf(e0)-1.f);
    float x1 = e1>0.f?e1:(__expf(e1)-1.f);
    float y0 = x0 + o1[s*2], y1 = x1 + o1[s*2+1];
    float mm = fmaxf(y0,y1);
    float p0 = __expf(y0-mm), p1=__expf(y1-mm);
    float is = 1.f/(p0+p1);
    float out0 = p0*is, out1 = p1*is;
    float m2 = fmaxf(out0,out1);
    float lse = m2 + logf(__expf(out0-m2)+__expf(out1-m2));
    float ol = (label[s]!=0) ? out1 : out0;
    lt[s] = lse - ol;
    dout[1 + s*2]   = out0;
    dout[2 + s*2]   = out1;
  }
  __syncthreads();
  if (tid==0) {
    float sum=0.f;
    for (int s=0;s<S_;++s) sum += lt[s];
    dout[0] = sum * (1.0f/(float)S_);
  }
}

// ---------------------------------------------------------------- launch
extern "C" void kernel_launch(void* const* d_in, const int* in_sizes, int n_in,
                              void* d_out, int out_size, void* d_ws, size_t ws_size,
                              hipStream_t stream) {
  const float* pg_Wih  = (const float*)d_in[0];
  const float* pg_Whh  = (const float*)d_in[1];
  const float* pg_bih  = (const float*)d_in[2];
  const float* pg_bhh  = (const float*)d_in[3];
  const float* pa_W    = (const float*)d_in[4];
  const float* pa_b    = (const float*)d_in[5];
  const float* tl_Wall = (const float*)d_in[6];
  const float* tl_bWall= (const float*)d_in[7];
  const float* tl_Uall = (const float*)d_in[8];
  const float* tl_bUall= (const float*)d_in[9];
  const float* tl_Wd   = (const float*)d_in[10];
  const float* tl_bd   = (const float*)d_in[11];
  const float* ta_W    = (const float*)d_in[12];
  const float* ta_b    = (const float*)d_in[13];
  const float* sg_Wih  = (const float*)d_in[14];
  const float* sg_Whh  = (const float*)d_in[15];
  const float* sg_bih  = (const float*)d_in[16];
  const float* sg_bhh  = (const float*)d_in[17];
  const float* sa_W    = (const float*)d_in[18];
  const float* sa_b    = (const float*)d_in[19];
  const float* bi_W    = (const float*)d_in[20];
  const float* bi_b    = (const float*)d_in[21];
  const float* bl_W    = (const float*)d_in[22];
  const float* bl_b    = (const float*)d_in[23];
  const float* mha_Wq  = (const float*)d_in[24];
  const float* mha_bq  = (const float*)d_in[25];
  const float* mha_Wk  = (const float*)d_in[26];
  const float* mha_bk  = (const float*)d_in[27];
  const float* fc_W    = (const float*)d_in[28];
  const float* fc_b    = (const float*)d_in[29];
  const float* text    = (const float*)d_in[30];
  const float* price   = (const float*)d_in[31];
  const float* tstamps = (const float*)d_in[32];
  const int*   label   = (const int*)d_in[33];
  (void)in_sizes; (void)n_in; (void)out_size; (void)ws_size;

  // workspace layout
  unsigned short* GXbf = (unsigned short*)d_ws;               // 30,720,000 us
  float* news   = (float*)(GXbf + (size_t)S_*M_*G4);          // 192,000 f
  float* xvec   = news + (size_t)S_*D_*H_;                    // 6,400 f
  float* feat   = xvec + (size_t)S_*H_;                       // 6,400 f
  float* Qg     = feat + (size_t)S_*H_;                       // 6,400 f
  float* Kg     = Qg   + (size_t)S_*H_;                       // 6,400 f
  float* scw    = Kg   + (size_t)S_*H_;                       // 40,000 f
  float* tvecg  = scw  + (size_t)4*S_*S_;                     // 6,400 f
  float* dout   = (float*)d_out;

  k_gemm<<<7600, 64, 0, stream>>>(text, tl_Wall, tl_bWall, tl_bUall, GXbf);
  k_recur<<<6*S_, 256, 0, stream>>>(GXbf, tl_Uall, tl_Wd, tl_bd, tstamps, ta_W, ta_b, news,
                                    price, pg_Wih, pg_Whh, pg_bih, pg_bhh, pa_W, pa_b, xvec);
  k_rnn<<<S_, 256, 0, stream>>>(news, sg_Wih, sg_Whh, sg_bih, sg_bhh, sa_W, sa_b, tvecg);
  k_bilin<<<4*S_, 256, 0, stream>>>(tvecg, xvec, bi_W, bi_b, feat);
  k_head<<<1, 1024, 0, stream>>>(feat, bl_W, bl_b, mha_Wq, mha_bq, mha_Wk, mha_bk, fc_W, fc_b, label, Qg, Kg, scw, dout);
}

// Round 13
// 403.011 us; speedup vs baseline: 1.2992x; 1.2992x over previous
//
#include <hip/hip_runtime.h>
#include <math.h>

#define S_  100
#define D_  30
#define T_  40
#define FT_ 512
#define FP_ 3
#define H_  64
#define G3  192
#define G4  256
#define M_  (D_*T_)   // 1200
#define NDY 6         // days per recur block
#define NGEMM 3800    // 100 stocks * 19 mb * 2 nb

typedef __attribute__((ext_vector_type(8))) short short8_t;
typedef __attribute__((ext_vector_type(4))) short short4_t;
typedef __attribute__((ext_vector_type(4))) float f32x4;

__device__ __forceinline__ float sigm(float x){ return 1.0f/(1.0f+__expf(-x)); }
__device__ __forceinline__ float tanhfast(float x){
  float e = __expf(2.0f*x);
  return 1.0f - 2.0f/(e + 1.0f);
}
__device__ __forceinline__ short f2bf(float f){
  unsigned u = __builtin_bit_cast(unsigned, f);
  u += 0x7FFFu + ((u>>16)&1u);
  return (short)(u>>16);
}
__device__ __forceinline__ float bf2f(unsigned short u){
  unsigned x = ((unsigned)u) << 16;
  return __builtin_bit_cast(float, x);
}
__device__ __forceinline__ short8_t pack8(float4 a, float4 b){
  short8_t o;
  o[0]=f2bf(a.x); o[1]=f2bf(a.y); o[2]=f2bf(a.z); o[3]=f2bf(a.w);
  o[4]=f2bf(b.x); o[5]=f2bf(b.y); o[6]=f2bf(b.z); o[7]=f2bf(b.w);
  return o;
}

// ---------------------------------------------------------------- K1: GX[s][m][gate] + fused price-GRU
// 64x128 tile, BK=32, 4 waves (2x2), 2-phase staging, 1 barrier/panel,
// double-buffered LDS, 39.4 KB -> 4 blocks/CU for cross-block overlap.
__global__ __launch_bounds__(256, 4) void k_gemm_price(
    const float* __restrict__ text, const float* __restrict__ Wall,
    const float* __restrict__ bW, const float* __restrict__ bU,
    unsigned short* __restrict__ GX,
    const float* __restrict__ price, const float* __restrict__ pWih,
    const float* __restrict__ pWhh, const float* __restrict__ pbih,
    const float* __restrict__ pbhh, const float* __restrict__ paW,
    const float* __restrict__ pab, float* __restrict__ xvec)
{
  __shared__ __align__(16) char smem[39424];
  const int tid = threadIdx.x;

  if (blockIdx.x < NGEMM) {
    // =================== GEMM path ===================
    const int orig = blockIdx.x;
    const int wg = (orig & 7) * 475 + (orig >> 3);   // bijective XCD swizzle (3800=8*475)
    const int s   = wg / 38;
    const int r38 = wg % 38;
    const int m0 = (r38 >> 1) * 64;
    const int n0 = (r38 & 1) * 128;
    const int lane = tid & 63, wave = tid >> 6;
    const int wm = wave >> 1, wn = wave & 1;          // 2x2 waves; wave tile 32x64
    const int fr = lane & 15, fk = (lane >> 4) * 8;

    float (*As)[64][36]  = (float(*)[64][36])smem;             // 18432 B
    short (*Bs)[128][40] = (short(*)[128][40])(smem + 18432);  // 20480 B
    float* biasL         = (float*)(smem + 38912);             // 512 B
    short (*Es)[136]     = (short(*)[136])smem;                // epilogue alias 17408 B

    if (tid < 128) biasL[tid] = bW[s*G4 + n0 + tid] + bU[s*G4 + n0 + tid];

    const float* X   = text + (size_t)s * ((size_t)M_*FT_);
    const float* Wsl = Wall + (size_t)s * ((size_t)G4*FT_);

    const int rowA = tid >> 2;            // 0..63
    const int colA = (tid & 3) * 8;       // 0,8,16,24
    int ar = m0 + rowA; if (ar > M_-1) ar = M_-1;
    const float* aSrc = X + (size_t)ar*FT_ + colA;
    const int rowB = tid >> 1;            // 0..127
    const int colB = (tid & 1) * 16;      // 0 or 16
    const float* bSrc = Wsl + (size_t)(n0 + rowB)*FT_ + colB;

    f32x4 acc[2][4];
    #pragma unroll
    for (int i=0;i<2;++i)
      #pragma unroll
      for (int j=0;j<4;++j) acc[i][j] = (f32x4)(0.f);

    float4 la0, la1, lb0, lb1, lb2, lb3;
    la0 = *reinterpret_cast<const float4*>(aSrc);
    la1 = *reinterpret_cast<const float4*>(aSrc + 4);
    lb0 = *reinterpret_cast<const float4*>(bSrc);
    lb1 = *reinterpret_cast<const float4*>(bSrc + 4);
    lb2 = *reinterpret_cast<const float4*>(bSrc + 8);
    lb3 = *reinterpret_cast<const float4*>(bSrc + 12);

    for (int kp = 0; kp < 16; ++kp) {
      const int buf = kp & 1;
      *reinterpret_cast<float4*>(&As[buf][rowA][colA])     = la0;
      *reinterpret_cast<float4*>(&As[buf][rowA][colA + 4]) = la1;
      *reinterpret_cast<short8_t*>(&Bs[buf][rowB][colB])     = pack8(lb0, lb1);
      *reinterpret_cast<short8_t*>(&Bs[buf][rowB][colB + 8]) = pack8(lb2, lb3);
      __syncthreads();
      if (kp + 1 < 16) {
        const int ko = (kp + 1) * 32;
        la0 = *reinterpret_cast<const float4*>(aSrc + ko);
        la1 = *reinterpret_cast<const float4*>(aSrc + ko + 4);
        lb0 = *reinterpret_cast<const float4*>(bSrc + ko);
        lb1 = *reinterpret_cast<const float4*>(bSrc + ko + 4);
        lb2 = *reinterpret_cast<const float4*>(bSrc + ko + 8);
        lb3 = *reinterpret_cast<const float4*>(bSrc + ko + 12);
      }
      short8_t bfr[4];
      #pragma unroll
      for (int nt = 0; nt < 4; ++nt)
        bfr[nt] = *reinterpret_cast<const short8_t*>(&Bs[buf][wn*64 + nt*16 + fr][fk]);
      #pragma unroll
      for (int mt = 0; mt < 2; ++mt) {
        float4 x = *reinterpret_cast<const float4*>(&As[buf][wm*32 + mt*16 + fr][fk]);
        float4 y = *reinterpret_cast<const float4*>(&As[buf][wm*32 + mt*16 + fr][fk + 4]);
        short8_t afr = pack8(x, y);
        #pragma unroll
        for (int nt = 0; nt < 4; ++nt)
          acc[mt][nt] = __builtin_amdgcn_mfma_f32_16x16x32_bf16(afr, bfr[nt], acc[mt][nt], 0,0,0);
      }
      // single barrier per panel: dbuf + transitivity keeps it race-free
    }

    // epilogue: LDS transpose -> coalesced bf16 stores
    __syncthreads();
    {
      const int l15 = lane & 15, rm = (lane >> 4) * 4;
      #pragma unroll
      for (int mt = 0; mt < 2; ++mt)
        #pragma unroll
        for (int nt = 0; nt < 4; ++nt) {
          const int cc = wn*64 + nt*16 + l15;
          const float b = biasL[cc];
          #pragma unroll
          for (int r = 0; r < 4; ++r)
            Es[wm*32 + mt*16 + rm + r][cc] = f2bf(acc[mt][nt][r] + b);
        }
    }
    __syncthreads();
    {
      const int row = tid >> 2;
      const int c0 = (tid & 3) * 32;
      const int m = m0 + row;
      if (m < M_) {
        unsigned short* dst = GX + ((size_t)s*M_ + m)*G4 + n0 + c0;
        #pragma unroll
        for (int j = 0; j < 4; ++j)
          *reinterpret_cast<short8_t*>(dst + j*8) =
              *reinterpret_cast<const short8_t*>(&Es[row][c0 + j*8]);
      }
    }
    return;
  }

  // =================== price-GRU path (blocks NGEMM..NGEMM+99) ===================
  {
    const int s = blockIdx.x - NGEMM;
    float* base = (float*)smem;
    float* hs   = base;                                  // 64
    float (*outsb)[H_+1] = (float(*)[H_+1])(hs + 64);    // 30 x 65
    float* gsum = hs + 64 + D_*(H_+1);                   // 128
    float* gxn  = gsum + 128;                            // 64
    float* ghn  = gxn + 64;                              // 64
    float (*pt)[H_] = (float(*)[H_])(ghn + 64);          // 4 x 64
    float* vs   = ghn + 64 + 4*H_;                       // 64
    float* as_  = vs + 64;                               // 30
    const int row = tid & 63, q = (tid >> 6) & 3;

    float wih[3]; float whh[64]; float bihr=0.f, bhhr=0.f;
    if (tid < G3) {
      const float* wp = pWih + ((size_t)s*G3 + tid)*FP_;
      wih[0]=wp[0]; wih[1]=wp[1]; wih[2]=wp[2];
      const float* hp = pWhh + ((size_t)s*G3 + tid)*H_;
      #pragma unroll
      for (int j=0;j<64;++j) whh[j]=hp[j];
      bihr = pbih[s*G3+tid]; bhhr = pbhh[s*G3+tid];
    }
    if (tid < H_) hs[tid]=0.f;
    __syncthreads();

    for (int d=0; d<D_; ++d) {
      if (tid < G3) {
        const float* pp = price + ((size_t)s*D_ + d)*FP_;
        float p0=pp[0], p1=pp[1], p2=pp[2];
        float gx = bihr + wih[0]*p0 + wih[1]*p1 + wih[2]*p2;
        float gh = bhhr;
        const float4* h4p = reinterpret_cast<const float4*>(hs);
        #pragma unroll
        for (int j4=0;j4<16;++j4) {
          float4 hv=h4p[j4];
          gh = fmaf(whh[j4*4+0],hv.x,gh); gh = fmaf(whh[j4*4+1],hv.y,gh);
          gh = fmaf(whh[j4*4+2],hv.z,gh); gh = fmaf(whh[j4*4+3],hv.w,gh);
        }
        if (tid < 128) gsum[tid] = gx + gh;
        else { gxn[tid-128] = gx; ghn[tid-128] = gh; }
      }
      __syncthreads();
      if (tid < H_) {
        float r = sigm(gsum[tid]);
        float z = sigm(gsum[64+tid]);
        float n = tanhf(gxn[tid] + r*ghn[tid]);
        float h2 = (1.f-z)*n + z*hs[tid];
        hs[tid]=h2; outsb[d][tid]=h2;
      }
      __syncthreads();
    }
    {
      const float* Wp = paW + ((size_t)s*H_ + row)*H_ + q*16;
      float p = 0.f;
      #pragma unroll
      for (int j=0;j<16;++j) p = fmaf(Wp[j], hs[q*16+j], p);
      pt[q][row] = p;
    }
    __syncthreads();
    if (tid < H_) vs[tid] = pt[0][tid]+pt[1][tid]+pt[2][tid]+pt[3][tid] + pab[s*H_+tid];
    __syncthreads();
    if (tid < D_) {
      float sc = 0.f;
      for (int h=0;h<H_;++h) sc = fmaf(outsb[tid][h], vs[h], sc);
      as_[tid] = sc;
    }
    __syncthreads();
    if (tid == 0) {
      float m = -1e30f;
      for (int t=0;t<D_;++t) m = fmaxf(m, as_[t]);
      float sum = 0.f;
      for (int t=0;t<D_;++t) { float e = __expf(as_[t]-m); as_[t]=e; sum += e; }
      float inv = 1.0f/sum;
      for (int t=0;t<D_;++t) as_[t] *= inv;
    }
    __syncthreads();
    if (tid < H_) {
      float acc = 0.f;
      for (int t=0;t<D_;++t) acc = fmaf(as_[t], outsb[t][tid], acc);
      xvec[s*H_+tid] = acc;
    }
  }
}

// ---------------------------------------------------------------- K2: TimeLSTM (6 days/block) + folded day attention -> news
#define RECUR_STEP(T_CUR, GXU, GXP)                                           \
  {                                                                           \
    {                                                                         \
      const int tpf = ((T_CUR)+1 < T_) ? (T_CUR)+1 : (T_CUR);                 \
      const unsigned short* GXt = GX + ((size_t)s*M_ + d0*T_ + tpf)*G4;       \
      _Pragma("unroll")                                                       \
      for (int it = 0; it < 2; ++it) {                                        \
        int d = it*4 + wave;                                                  \
        if (d < NDY) {                                                        \
          const unsigned short* p = GXt + (size_t)d*T_*G4 + lane;             \
          GXP[it][0]=bf2f(p[0]);   GXP[it][1]=bf2f(p[64]);                    \
          GXP[it][2]=bf2f(p[128]); GXP[it][3]=bf2f(p[192]);                   \
        }                                                                     \
      }                                                                       \
    }                                                                         \
    f32x4 acc1_0=(f32x4)(0.f), acc1_1=(f32x4)(0.f);                           \
    f32x4 acc1_2=(f32x4)(0.f), acc1_3=(f32x4)(0.f);                           \
    f32x4 acc2=(f32x4)(0.f);                                                  \
    _Pragma("unroll")                                                         \
    for (int kw = 0; kw < 2; ++kw) {                                          \
      short8_t bfrag = *reinterpret_cast<const short8_t*>(&Hn[fr][kw*32+fk]); \
      acc1_0 = __builtin_amdgcn_mfma_f32_16x16x32_bf16(ureg[0][kw], bfrag, acc1_0,0,0,0); \
      acc1_1 = __builtin_amdgcn_mfma_f32_16x16x32_bf16(ureg[1][kw], bfrag, acc1_1,0,0,0); \
      acc1_2 = __builtin_amdgcn_mfma_f32_16x16x32_bf16(ureg[2][kw], bfrag, acc1_2,0,0,0); \
      acc1_3 = __builtin_amdgcn_mfma_f32_16x16x32_bf16(ureg[3][kw], bfrag, acc1_3,0,0,0); \
      short8_t cfrag = *reinterpret_cast<const short8_t*>(&Cn[fr][kw*32+fk]); \
      acc2 = __builtin_amdgcn_mfma_f32_16x16x32_bf16(wdreg[kw], cfrag, acc2,0,0,0); \
    }                                                                         \
    *reinterpret_cast<f32x4*>(&G1[l15][wave*64 +  0 + h4]) = acc1_0;          \
    *reinterpret_cast<f32x4*>(&G1[l15][wave*64 + 16 + h4]) = acc1_1;          \
    *reinterpret_cast<f32x4*>(&G1[l15][wave*64 + 32 + h4]) = acc1_2;          \
    *reinterpret_cast<f32x4*>(&G1[l15][wave*64 + 48 + h4]) = acc1_3;          \
    *reinterpret_cast<f32x4*>(&G2l[l15][wave*16 + h4]) = acc2;                \
    __syncthreads();                                                          \
    _Pragma("unroll")                                                         \
    for (int it = 0; it < 2; ++it) {                                          \
      int d = it*4 + wave;                                                    \
      if (d < NDY) {                                                          \
        float gf = G1[d][lane]       + GXU[it][0];                            \
        float gi = G1[d][64 + lane]  + GXU[it][1];                            \
        float go = G1[d][128 + lane] + GXU[it][2];                            \
        float gc = G1[d][192 + lane] + GXU[it][3];                            \
        float f  = sigm(gf), ig = sigm(gi), og = sigm(go), ct = sigm(gc);     \
        float cs1 = tanhfast(G2l[d][lane] + bdl[lane]);                       \
        float tvv = tsl[d][(T_CUR)];                                          \
        float c  = Cf[d][lane];                                               \
        float cadj = c - cs1 + cs1*tvv;                                       \
        float c2 = f*cadj + ig*ct;                                            \
        float h2 = og*tanhfast(c2);                                           \
        Cf[d][lane] = c2; Cn[d][lane] = f2bf(c2); Hn[d][lane] = f2bf(h2);     \
        outs_lds[d][(T_CUR)][lane] = f2bf(h2);                                \
      }                                                                       \
    }                                                                         \
    __syncthreads();                                                          \
  }

__global__ __launch_bounds__(256) void k_recur(
    const unsigned short* __restrict__ GX, const float* __restrict__ Uall,
    const float* __restrict__ Wd, const float* __restrict__ bd,
    const float* __restrict__ ts, const float* __restrict__ taW,
    const float* __restrict__ tab, float* __restrict__ news)
{
  const int bid = blockIdx.x;
  const int s  = bid / 5;
  const int d0 = (bid % 5) * NDY;
  const int tid = threadIdx.x;
  const int lane = tid & 63, wave = tid >> 6;
  const int fr = lane & 15, fk = (lane >> 4) * 8;
  const int l15 = lane & 15, h4 = (lane >> 4) * 4;

  __shared__ float G1[16][260];
  __shared__ float G2l[16][68];
  __shared__ float Cf[8][68];
  __shared__ short Hn[16][72];
  __shared__ short Cn[16][72];
  __shared__ float tsl[NDY][T_];
  __shared__ float bdl[H_], tabl[H_];
  __shared__ float scl[NDY][T_];
  __shared__ short outs_lds[NDY][T_][68];

  for (int e = tid; e < 16*72; e += 256) { (&Hn[0][0])[e] = 0; (&Cn[0][0])[e] = 0; }
  for (int e = tid; e < 8*68; e += 256) (&Cf[0][0])[e] = 0.f;
  for (int e = tid; e < NDY*T_; e += 256)
    (&tsl[0][0])[e] = ts[((size_t)s*D_ + d0)*T_ + e];
  if (tid < H_) { bdl[tid] = bd[s*H_ + tid]; tabl[tid] = tab[s*H_ + tid]; }

  short8_t ureg[4][2], wdreg[2], twreg[2];
  {
    const float* Uf  = Uall + (size_t)s*G4*H_;
    const float* Wdf = Wd   + (size_t)s*H_*H_;
    const float* Twf = taW  + (size_t)s*H_*H_;
    #pragma unroll
    for (int mt = 0; mt < 4; ++mt)
      #pragma unroll
      for (int kw = 0; kw < 2; ++kw) {
        const float* p = Uf + (size_t)(wave*64 + mt*16 + fr)*H_ + kw*32 + fk;
        ureg[mt][kw] = pack8(*reinterpret_cast<const float4*>(p),
                             *reinterpret_cast<const float4*>(p + 4));
      }
    #pragma unroll
    for (int kw = 0; kw < 2; ++kw) {
      const float* p = Wdf + (size_t)(wave*16 + fr)*H_ + kw*32 + fk;
      wdreg[kw] = pack8(*reinterpret_cast<const float4*>(p),
                        *reinterpret_cast<const float4*>(p + 4));
      const float* q = Twf + (size_t)(wave*16 + fr)*H_ + kw*32 + fk;
      twreg[kw] = pack8(*reinterpret_cast<const float4*>(q),
                        *reinterpret_cast<const float4*>(q + 4));
    }
  }
  __syncthreads();

  float gxA[2][4], gxB[2][4];
  {
    const unsigned short* GXt = GX + ((size_t)s*M_ + d0*T_)*G4;
    #pragma unroll
    for (int it = 0; it < 2; ++it) {
      int d = it*4 + wave;
      if (d < NDY) {
        const unsigned short* p = GXt + (size_t)d*T_*G4 + lane;
        gxA[it][0]=bf2f(p[0]);   gxA[it][1]=bf2f(p[64]);
        gxA[it][2]=bf2f(p[128]); gxA[it][3]=bf2f(p[192]);
      }
    }
  }

  for (int t = 0; t < T_; t += 2) {
    RECUR_STEP(t,   gxA, gxB)
    RECUR_STEP(t+1, gxB, gxA)
  }

  // ---- folded day attention ----
  {
    f32x4 accv = (f32x4)(0.f);
    #pragma unroll
    for (int kw = 0; kw < 2; ++kw) {
      short8_t hfr = *reinterpret_cast<const short8_t*>(&Hn[fr][kw*32+fk]);
      accv = __builtin_amdgcn_mfma_f32_16x16x32_bf16(twreg[kw], hfr, accv, 0,0,0);
    }
    *reinterpret_cast<f32x4*>(&G2l[l15][wave*16 + h4]) = accv;
  }
  __syncthreads();
  for (int e = tid; e < NDY*H_; e += 256) {
    int d = e >> 6, i = e & 63;
    G2l[d][i] += tabl[i];
  }
  __syncthreads();
  for (int idx = tid; idx < NDY*T_; idx += 256) {
    int d = idx / T_, t = idx % T_;
    float sc = 0.f;
    #pragma unroll 8
    for (int l = 0; l < H_; ++l)
      sc = fmaf(bf2f((unsigned short)outs_lds[d][t][l]), G2l[d][l], sc);
    scl[d][t] = sc;
  }
  __syncthreads();
  if (tid < NDY) {
    float m = -1e30f;
    for (int t = 0; t < T_; ++t) m = fmaxf(m, scl[tid][t]);
    float sum = 0.f;
    for (int t = 0; t < T_; ++t) { float e = __expf(scl[tid][t]-m); scl[tid][t]=e; sum+=e; }
    float inv = 1.f/sum;
    for (int t = 0; t < T_; ++t) scl[tid][t] *= inv;
  }
  __syncthreads();
  {
    const int l = tid & 63, w = tid >> 6;
    for (int d = w; d < NDY; d += 4) {
      float o = 0.f;
      #pragma unroll 8
      for (int t = 0; t < T_; ++t)
        o = fmaf(scl[d][t], bf2f((unsigned short)outs_lds[d][t][l]), o);
      news[((size_t)s*D_ + d0 + d)*H_ + l] = o;
    }
  }
}

// ---------------------------------------------------------------- K4: stock-GRU over news + attention -> tvec
__global__ __launch_bounds__(256) void k_rnn(
    const float* __restrict__ news, const float* __restrict__ sWih,
    const float* __restrict__ sWhh, const float* __restrict__ sbih,
    const float* __restrict__ sbhh, const float* __restrict__ saW,
    const float* __restrict__ sab, float* __restrict__ tvecg)
{
  const int s = blockIdx.x;
  const int tid = threadIdx.x;
  const int row = tid & 63, q = tid >> 6;
  __shared__ float xs[H_], hs[H_];
  __shared__ float outsb[D_][H_+1];
  __shared__ float gsum[128], gxn[64], ghn[64];
  __shared__ float pt[4][H_], vs[H_], as_[D_];

  float wih[64]; float whh[64]; float bihr=0.f, bhhr=0.f;
  if (tid < G3) {
    const float* wp = sWih + ((size_t)s*G3 + tid)*H_;
    const float* hp = sWhh + ((size_t)s*G3 + tid)*H_;
    #pragma unroll
    for (int j=0;j<64;++j) { wih[j]=wp[j]; whh[j]=hp[j]; }
    bihr = sbih[s*G3+tid]; bhhr = sbhh[s*G3+tid];
  }
  if (tid < H_) hs[tid]=0.f;
  __syncthreads();

  for (int d=0; d<D_; ++d) {
    if (tid < H_) xs[tid] = news[((size_t)s*D_ + d)*H_ + tid];
    __syncthreads();
    if (tid < G3) {
      float gx = bihr, gh = bhhr;
      const float4* x4 = reinterpret_cast<const float4*>(xs);
      const float4* h4p = reinterpret_cast<const float4*>(hs);
      #pragma unroll
      for (int j4=0;j4<16;++j4) {
        float4 xv=x4[j4]; float4 hv=h4p[j4];
        gx = fmaf(wih[j4*4+0],xv.x,gx); gx = fmaf(wih[j4*4+1],xv.y,gx);
        gx = fmaf(wih[j4*4+2],xv.z,gx); gx = fmaf(wih[j4*4+3],xv.w,gx);
        gh = fmaf(whh[j4*4+0],hv.x,gh); gh = fmaf(whh[j4*4+1],hv.y,gh);
        gh = fmaf(whh[j4*4+2],hv.z,gh); gh = fmaf(whh[j4*4+3],hv.w,gh);
      }
      if (tid < 128) gsum[tid] = gx + gh;
      else { gxn[tid-128] = gx; ghn[tid-128] = gh; }
    }
    __syncthreads();
    if (tid < H_) {
      float r = sigm(gsum[tid]);
      float z = sigm(gsum[64+tid]);
      float n = tanhf(gxn[tid] + r*ghn[tid]);
      float h2 = (1.f-z)*n + z*hs[tid];
      hs[tid]=h2; outsb[d][tid]=h2;
    }
    __syncthreads();
  }

  {
    const float* Wp = saW + ((size_t)s*H_ + row)*H_ + q*16;
    float p = 0.f;
    #pragma unroll
    for (int j=0;j<16;++j) p = fmaf(Wp[j], hs[q*16+j], p);
    pt[q][row] = p;
    __syncthreads();
    if (tid < H_) vs[tid] = pt[0][tid]+pt[1][tid]+pt[2][tid]+pt[3][tid] + sab[s*H_+tid];
    __syncthreads();
    if (tid < D_) {
      float sc = 0.f;
      for (int h=0;h<H_;++h) sc = fmaf(outsb[tid][h], vs[h], sc);
      as_[tid] = sc;
    }
    __syncthreads();
    if (tid == 0) {
      float m = -1e30f;
      for (int t=0;t<D_;++t) m = fmaxf(m, as_[t]);
      float sum = 0.f;
      for (int t=0;t<D_;++t) { float e = __expf(as_[t]-m); as_[t]=e; sum += e; }
      float inv = 1.0f/sum;
      for (int t=0;t<D_;++t) as_[t] *= inv;
    }
    __syncthreads();
    if (tid < H_) {
      float acc = 0.f;
      for (int t=0;t<D_;++t) acc = fmaf(as_[t], outsb[t][tid], acc);
      tvecg[s*H_+tid] = acc;
    }
  }
}

// ---------------------------------------------------------------- K5b: bilinear -> feat
__global__ __launch_bounds__(256) void k_bilin(
    const float* __restrict__ tvec, const float* __restrict__ xvec,
    const float* __restrict__ biW, const float* __restrict__ bib,
    float* __restrict__ feat)
{
  const int s = blockIdx.x >> 2;
  const int k0 = (blockIdx.x & 3) * 16;
  const int tid = threadIdx.x;
  const int lane = tid & 63, w = tid >> 6;
  __shared__ float pmat[H_*H_];
  __shared__ float tl[H_], xl[H_];
  if (tid < H_) { tl[tid] = tvec[s*H_+tid]; xl[tid] = xvec[s*H_+tid]; }
  __syncthreads();
  for (int e = tid; e < H_*H_; e += 256) pmat[e] = tl[e>>6]*xl[e&63];
  __syncthreads();
  const float4* P4 = reinterpret_cast<const float4*>(pmat);
  #pragma unroll
  for (int kk = 0; kk < 4; ++kk) {
    int k = k0 + kk*4 + w;
    const float4* W4 = reinterpret_cast<const float4*>(biW + ((size_t)s*H_ + k)*H_*H_);
    float acc = 0.f;
    #pragma unroll
    for (int r = 0; r < 16; ++r) {
      float4 wv = W4[r*64 + lane];
      float4 pv = P4[r*64 + lane];
      acc += wv.x*pv.x + wv.y*pv.y + wv.z*pv.z + wv.w*pv.w;
    }
    #pragma unroll
    for (int off = 32; off > 0; off >>= 1) acc += __shfl_down(acc, off, 64);
    if (lane == 0) feat[s*H_ + k] = tanhf(acc + bib[s*H_+k]);
  }
}

// ---------------------------------------------------------------- K6: head
__global__ __launch_bounds__(1024) void k_head(
    const float* __restrict__ feat, const float* __restrict__ blW,
    const float* __restrict__ blb, const float* __restrict__ Wq,
    const float* __restrict__ bq, const float* __restrict__ Wk,
    const float* __restrict__ bk, const float* __restrict__ fcW,
    const float* __restrict__ fcb, const int* __restrict__ label,
    float* __restrict__ Qg, float* __restrict__ Kg, float* __restrict__ scw,
    float* __restrict__ dout)
{
  const int tid = threadIdx.x;
  __shared__ float fs[S_*H_];
  __shared__ float mhs[S_*H_];
  __shared__ float o1[S_*2];
  __shared__ float lt[S_];

  for (int e=tid; e<S_*H_; e+=1024) fs[e] = feat[e];
  __syncthreads();

  if (tid < 2*S_) {
    int s = tid>>1, c = tid&1;
    const float* w = blW + ((size_t)(S_-1)*2 + c)*H_;
    float a = blb[(S_-1)*2 + c];
    for (int h=0;h<H_;++h) a = fmaf(fs[s*H_+h], w[h], a);
    o1[tid] = tanhf(a);
  }
  for (int e=tid; e<S_*H_; e+=1024) {
    int s = e>>6, o = e&63;
    float aq = bq[o], ak = bk[o];
    const float* wq = Wq + o*H_;
    const float* wk = Wk + o*H_;
    for (int h=0;h<H_;++h) { float f = fs[s*H_+h]; aq = fmaf(f, wq[h], aq); ak = fmaf(f, wk[h], ak); }
    Qg[e]=aq; Kg[e]=ak;
  }
  __syncthreads();

  if (tid < 4*S_) {
    int s = tid % S_, hd = tid / S_;
    const float* qr = Qg + s*H_ + hd*16;
    float m = -1e30f;
    for (int t=0;t<S_;++t) {
      const float* kr = Kg + t*H_ + hd*16;
      float sc=0.f;
      #pragma unroll
      for (int d2=0; d2<16; ++d2) sc = fmaf(qr[d2], kr[d2], sc);
      sc *= 0.25f;
      scw[(size_t)tid*S_+t]=sc;
      m = fmaxf(m, sc);
    }
    float sum=0.f;
    for (int t=0;t<S_;++t) { float e=__expf(scw[(size_t)tid*S_+t]-m); scw[(size_t)tid*S_+t]=e; sum+=e; }
    float inv=1.f/sum;
    float acc[16];
    #pragma unroll
    for (int d2=0;d2<16;++d2) acc[d2]=0.f;
    for (int t=0;t<S_;++t) {
      float a = scw[(size_t)tid*S_+t]*inv;
      #pragma unroll
      for (int d2=0;d2<16;++d2) acc[d2] = fmaf(a, fs[t*H_ + hd*16 + d2], acc[d2]);
    }
    #pragma unroll
    for (int d2=0;d2<16;++d2) mhs[s*H_ + hd*16 + d2] = acc[d2];
  }
  __syncthreads();

  if (tid < S_) {
    int s = tid;
    float e0 = fcb[0], e1 = fcb[1];
    for (int h=0;h<H_;++h) { float mv = mhs[s*H_+h]; e0 = fmaf(mv, fcW[h], e0); e1 = fmaf(mv, fcW[H_+h], e1); }
    float x0 = e0>0.f?e0:(__expf(e0)-1.f);
    float x1 = e1>0.f?e1:(__expf(e1)-1.f);
    float y0 = x0 + o1[s*2], y1 = x1 + o1[s*2+1];
    float mm = fmaxf(y0,y1);
    float p0 = __expf(y0-mm), p1=__expf(y1-mm);
    float is = 1.f/(p0+p1);
    float out0 = p0*is, out1 = p1*is;
    float m2 = fmaxf(out0,out1);
    float lse = m2 + logf(__expf(out0-m2)+__expf(out1-m2));
    float ol = (label[s]!=0) ? out1 : out0;
    lt[s] = lse - ol;
    dout[1 + s*2]   = out0;
    dout[2 + s*2]   = out1;
  }
  __syncthreads();
  if (tid==0) {
    float sum=0.f;
    for (int s=0;s<S_;++s) sum += lt[s];
    dout[0] = sum * (1.0f/(float)S_);
  }
}

// ---------------------------------------------------------------- launch
extern "C" void kernel_launch(void* const* d_in, const int* in_sizes, int n_in,
                              void* d_out, int out_size, void* d_ws, size_t ws_size,
                              hipStream_t stream) {
  const float* pg_Wih  = (const float*)d_in[0];
  const float* pg_Whh  = (const float*)d_in[1];
  const float* pg_bih  = (const float*)d_in[2];
  const float* pg_bhh  = (const float*)d_in[3];
  const float* pa_W    = (const float*)d_in[4];
  const float* pa_b    = (const float*)d_in[5];
  const float* tl_Wall = (const float*)d_in[6];
  const float* tl_bWall= (const float*)d_in[7];
  const float* tl_Uall = (const float*)d_in[8];
  const float* tl_bUall= (const float*)d_in[9];
  const float* tl_Wd   = (const float*)d_in[10];
  const float* tl_bd   = (const float*)d_in[11];
  const float* ta_W    = (const float*)d_in[12];
  const float* ta_b    = (const float*)d_in[13];
  const float* sg_Wih  = (const float*)d_in[14];
  const float* sg_Whh  = (const float*)d_in[15];
  const float* sg_bih  = (const float*)d_in[16];
  const float* sg_bhh  = (const float*)d_in[17];
  const float* sa_W    = (const float*)d_in[18];
  const float* sa_b    = (const float*)d_in[19];
  const float* bi_W    = (const float*)d_in[20];
  const float* bi_b    = (const float*)d_in[21];
  const float* bl_W    = (const float*)d_in[22];
  const float* bl_b    = (const float*)d_in[23];
  const float* mha_Wq  = (const float*)d_in[24];
  const float* mha_bq  = (const float*)d_in[25];
  const float* mha_Wk  = (const float*)d_in[26];
  const float* mha_bk  = (const float*)d_in[27];
  const float* fc_W    = (const float*)d_in[28];
  const float* fc_b    = (const float*)d_in[29];
  const float* text    = (const float*)d_in[30];
  const float* price   = (const float*)d_in[31];
  const float* tstamps = (const float*)d_in[32];
  const int*   label   = (const int*)d_in[33];
  (void)in_sizes; (void)n_in; (void)out_size; (void)ws_size;

  // workspace layout
  unsigned short* GXbf = (unsigned short*)d_ws;               // 30,720,000 us
  float* news   = (float*)(GXbf + (size_t)S_*M_*G4);          // 192,000 f
  float* xvec   = news + (size_t)S_*D_*H_;                    // 6,400 f
  float* feat   = xvec + (size_t)S_*H_;                       // 6,400 f
  float* Qg     = feat + (size_t)S_*H_;                       // 6,400 f
  float* Kg     = Qg   + (size_t)S_*H_;                       // 6,400 f
  float* scw    = Kg   + (size_t)S_*H_;                       // 40,000 f
  float* tvecg  = scw  + (size_t)4*S_*S_;                     // 6,400 f
  float* dout   = (float*)d_out;

  k_gemm_price<<<NGEMM + S_, 256, 0, stream>>>(text, tl_Wall, tl_bWall, tl_bUall, GXbf,
                                               price, pg_Wih, pg_Whh, pg_bih, pg_bhh,
                                               pa_W, pa_b, xvec);
  k_recur<<<5*S_, 256, 0, stream>>>(GXbf, tl_Uall, tl_Wd, tl_bd, tstamps, ta_W, ta_b, news);
  k_rnn<<<S_, 256, 0, stream>>>(news, sg_Wih, sg_Whh, sg_bih, sg_bhh, sa_W, sa_b, tvecg);
  k_bilin<<<4*S_, 256, 0, stream>>>(tvecg, xvec, bi_W, bi_b, feat);
  k_head<<<1, 1024, 0, stream>>>(feat, bl_W, bl_b, mha_Wq, mha_bq, mha_Wk, mha_bk, fc_W, fc_b, label, Qg, Kg, scw, dout);
}

// Round 14
// 281.455 us; speedup vs baseline: 1.8604x; 1.4319x over previous
//
#include <hip/hip_runtime.h>
#include <math.h>

#define S_  100
#define D_  30
#define T_  40
#define FT_ 512
#define FP_ 3
#define H_  64
#define G3  192
#define G4  256
#define M_  (D_*T_)   // 1200
#define NDY 6         // days per recur block

typedef __attribute__((ext_vector_type(8))) short short8_t;
typedef __attribute__((ext_vector_type(4))) short short4_t;
typedef __attribute__((ext_vector_type(4))) float f32x4;

__device__ __forceinline__ float sigm(float x){ return 1.0f/(1.0f+__expf(-x)); }
__device__ __forceinline__ float tanhfast(float x){
  float e = __expf(2.0f*x);
  return 1.0f - 2.0f/(e + 1.0f);
}
__device__ __forceinline__ short f2bf(float f){
  unsigned u = __builtin_bit_cast(unsigned, f);
  u += 0x7FFFu + ((u>>16)&1u);
  return (short)(u>>16);
}
__device__ __forceinline__ float bf2f(unsigned short u){
  unsigned x = ((unsigned)u) << 16;
  return __builtin_bit_cast(float, x);
}
__device__ __forceinline__ short8_t pack8(float4 a, float4 b){
  short8_t o;
  o[0]=f2bf(a.x); o[1]=f2bf(a.y); o[2]=f2bf(a.z); o[3]=f2bf(a.w);
  o[4]=f2bf(b.x); o[5]=f2bf(b.y); o[6]=f2bf(b.z); o[7]=f2bf(b.w);
  return o;
}

// ---------------------------------------------------------------- K1: GX[s][m][gate] + fused price-GRU (R10 config, 154 us measured)
__global__ __launch_bounds__(512, 2) void k_gemm_price(
    const float* __restrict__ text, const float* __restrict__ Wall,
    const float* __restrict__ bW, const float* __restrict__ bU,
    unsigned short* __restrict__ GX,
    const float* __restrict__ price, const float* __restrict__ pWih,
    const float* __restrict__ pWhh, const float* __restrict__ pbih,
    const float* __restrict__ pbhh, const float* __restrict__ paW,
    const float* __restrict__ pab, float* __restrict__ xvec)
{
  __shared__ __align__(16) char smem[78848];
  const int tid = threadIdx.x;

  if (blockIdx.x < 1000) {
    // =================== GEMM path ===================
    const int orig = blockIdx.x;
    const int wg = (orig & 7) * 125 + (orig >> 3);   // bijective XCD swizzle
    const int s  = wg / 10;
    const int mb = wg % 10;
    const int m0 = mb * 128;
    const int lane = tid & 63, wave = tid >> 6;
    const int wm = wave >> 2, wn = wave & 3;          // 2x4 waves, 64x64 each
    const int fr = lane & 15, fk = (lane >> 4) * 8;

    float (*As)[128][36] = (float(*)[128][36])smem;            // 36864 B
    short (*Bs)[G4][40]  = (short(*)[G4][40])(smem + 36864);   // 40960 B
    short (*Es)[264]     = (short(*)[264])smem;                // 67584 B (alias)
    float* biasL         = (float*)(smem + 77824);             // 1024 B

    if (tid < G4) biasL[tid] = bW[s*G4 + tid] + bU[s*G4 + tid];

    const float* X   = text + (size_t)s * ((size_t)M_*FT_);
    const float* Wsl = Wall + (size_t)s * ((size_t)G4*FT_);

    const int rowA = tid >> 2;             // 0..127
    const int colA = (tid & 3) * 8;        // 0,8,16,24
    int ar = m0 + rowA; if (ar > M_-1) ar = M_-1;
    const float* aSrc = X + (size_t)ar*FT_ + colA;
    const int rowB = tid >> 1;             // 0..255
    const int colB = (tid & 1) * 16;       // 0 or 16
    const float* bSrc = Wsl + (size_t)rowB*FT_ + colB;

    f32x4 acc[4][4];
    #pragma unroll
    for (int i=0;i<4;++i)
      #pragma unroll
      for (int j=0;j<4;++j) acc[i][j] = (f32x4)(0.f);

    float4 la0, la1, lb0, lb1, lb2, lb3;
    la0 = *reinterpret_cast<const float4*>(aSrc);
    la1 = *reinterpret_cast<const float4*>(aSrc + 4);
    lb0 = *reinterpret_cast<const float4*>(bSrc);
    lb1 = *reinterpret_cast<const float4*>(bSrc + 4);
    lb2 = *reinterpret_cast<const float4*>(bSrc + 8);
    lb3 = *reinterpret_cast<const float4*>(bSrc + 12);

    for (int kp = 0; kp < 16; ++kp) {
      const int buf = kp & 1;
      *reinterpret_cast<float4*>(&As[buf][rowA][colA])     = la0;
      *reinterpret_cast<float4*>(&As[buf][rowA][colA + 4]) = la1;
      *reinterpret_cast<short8_t*>(&Bs[buf][rowB][colB])     = pack8(lb0, lb1);
      *reinterpret_cast<short8_t*>(&Bs[buf][rowB][colB + 8]) = pack8(lb2, lb3);
      __syncthreads();
      if (kp + 1 < 16) {
        const int ko = (kp + 1) * 32;
        la0 = *reinterpret_cast<const float4*>(aSrc + ko);
        la1 = *reinterpret_cast<const float4*>(aSrc + ko + 4);
        lb0 = *reinterpret_cast<const float4*>(bSrc + ko);
        lb1 = *reinterpret_cast<const float4*>(bSrc + ko + 4);
        lb2 = *reinterpret_cast<const float4*>(bSrc + ko + 8);
        lb3 = *reinterpret_cast<const float4*>(bSrc + ko + 12);
      }
      short8_t bfr[4];
      #pragma unroll
      for (int nt = 0; nt < 4; ++nt)
        bfr[nt] = *reinterpret_cast<const short8_t*>(&Bs[buf][wn*64 + nt*16 + fr][fk]);
      #pragma unroll
      for (int mt = 0; mt < 4; ++mt) {
        float4 x = *reinterpret_cast<const float4*>(&As[buf][wm*64 + mt*16 + fr][fk]);
        float4 y = *reinterpret_cast<const float4*>(&As[buf][wm*64 + mt*16 + fr][fk + 4]);
        short8_t afr = pack8(x, y);
        #pragma unroll
        for (int nt = 0; nt < 4; ++nt)
          acc[mt][nt] = __builtin_amdgcn_mfma_f32_16x16x32_bf16(afr, bfr[nt], acc[mt][nt], 0,0,0);
      }
    }

    // epilogue: LDS transpose -> coalesced bf16 stores
    __syncthreads();
    {
      const int cl = lane & 15, rh = (lane >> 4) * 4;
      #pragma unroll
      for (int mt = 0; mt < 4; ++mt)
        #pragma unroll
        for (int nt = 0; nt < 4; ++nt) {
          const int cc = wn*64 + nt*16 + cl;
          const float b = biasL[cc];
          #pragma unroll
          for (int r = 0; r < 4; ++r)
            Es[wm*64 + mt*16 + rh + r][cc] = f2bf(acc[mt][nt][r] + b);
        }
    }
    __syncthreads();
    {
      const int r = tid >> 2;
      const int c0 = (tid & 3) * 64;
      const int m = m0 + r;
      if (m < M_) {
        unsigned short* dst = GX + ((size_t)s*M_ + m)*G4 + c0;
        #pragma unroll
        for (int j = 0; j < 8; ++j)
          *reinterpret_cast<short8_t*>(dst + j*8) =
              *reinterpret_cast<const short8_t*>(&Es[r][c0 + j*8]);
      }
    }
    return;
  }

  // =================== price-GRU path (blocks 1000..1099) ===================
  {
    const int s = blockIdx.x - 1000;
    float* hs   = (float*)smem;                                  // 64
    float (*outsb)[H_+1] = (float(*)[H_+1])(hs + 64);            // 30 x 65
    float* gsum = hs + 64 + D_*(H_+1);                           // 128
    float* gxn  = gsum + 128;                                    // 64
    float* ghn  = gxn + 64;                                      // 64
    float (*pt)[H_] = (float(*)[H_])(ghn + 64);                  // 4 x 64
    float* vs   = ghn + 64 + 4*H_;                               // 64
    float* as_  = vs + 64;                                       // 30
    const int row = tid & 63, q = (tid >> 6) & 3;

    float wih[3]; float whh[64]; float bihr=0.f, bhhr=0.f;
    if (tid < G3) {
      const float* wp = pWih + ((size_t)s*G3 + tid)*FP_;
      wih[0]=wp[0]; wih[1]=wp[1]; wih[2]=wp[2];
      const float* hp = pWhh + ((size_t)s*G3 + tid)*H_;
      #pragma unroll
      for (int j=0;j<64;++j) whh[j]=hp[j];
      bihr = pbih[s*G3+tid]; bhhr = pbhh[s*G3+tid];
    }
    if (tid < H_) hs[tid]=0.f;
    __syncthreads();

    for (int d=0; d<D_; ++d) {
      if (tid < G3) {
        const float* pp = price + ((size_t)s*D_ + d)*FP_;
        float p0=pp[0], p1=pp[1], p2=pp[2];
        float gx = bihr + wih[0]*p0 + wih[1]*p1 + wih[2]*p2;
        float gh = bhhr;
        const float4* h4p = reinterpret_cast<const float4*>(hs);
        #pragma unroll
        for (int j4=0;j4<16;++j4) {
          float4 hv=h4p[j4];
          gh = fmaf(whh[j4*4+0],hv.x,gh); gh = fmaf(whh[j4*4+1],hv.y,gh);
          gh = fmaf(whh[j4*4+2],hv.z,gh); gh = fmaf(whh[j4*4+3],hv.w,gh);
        }
        if (tid < 128) gsum[tid] = gx + gh;
        else { gxn[tid-128] = gx; ghn[tid-128] = gh; }
      }
      __syncthreads();
      if (tid < H_) {
        float r = sigm(gsum[tid]);
        float z = sigm(gsum[64+tid]);
        float n = tanhf(gxn[tid] + r*ghn[tid]);
        float h2 = (1.f-z)*n + z*hs[tid];
        hs[tid]=h2; outsb[d][tid]=h2;
      }
      __syncthreads();
    }
    if (tid < 256) {
      const float* Wp = paW + ((size_t)s*H_ + row)*H_ + q*16;
      float p = 0.f;
      #pragma unroll
      for (int j=0;j<16;++j) p = fmaf(Wp[j], hs[q*16+j], p);
      pt[q][row] = p;
    }
    __syncthreads();
    if (tid < H_) vs[tid] = pt[0][tid]+pt[1][tid]+pt[2][tid]+pt[3][tid] + pab[s*H_+tid];
    __syncthreads();
    if (tid < D_) {
      float sc = 0.f;
      for (int h=0;h<H_;++h) sc = fmaf(outsb[tid][h], vs[h], sc);
      as_[tid] = sc;
    }
    __syncthreads();
    if (tid == 0) {
      float m = -1e30f;
      for (int t=0;t<D_;++t) m = fmaxf(m, as_[t]);
      float sum = 0.f;
      for (int t=0;t<D_;++t) { float e = __expf(as_[t]-m); as_[t]=e; sum += e; }
      float inv = 1.0f/sum;
      for (int t=0;t<D_;++t) as_[t] *= inv;
    }
    __syncthreads();
    if (tid < H_) {
      float acc = 0.f;
      for (int t=0;t<D_;++t) acc = fmaf(as_[t], outsb[t][tid], acc);
      xvec[s*H_+tid] = acc;
    }
  }
}

// ---------------------------------------------------------------- K2: TimeLSTM (6 days/block) + folded day attention -> news
#define RECUR_STEP(T_CUR, GXU, GXP)                                           \
  {                                                                           \
    {                                                                         \
      const int tpf = ((T_CUR)+1 < T_) ? (T_CUR)+1 : (T_CUR);                 \
      const unsigned short* GXt = GX + ((size_t)s*M_ + d0*T_ + tpf)*G4;       \
      _Pragma("unroll")                                                       \
      for (int it = 0; it < 2; ++it) {                                        \
        int d = it*4 + wave;                                                  \
        if (d < NDY) {                                                        \
          const unsigned short* p = GXt + (size_t)d*T_*G4 + lane;             \
          GXP[it][0]=bf2f(p[0]);   GXP[it][1]=bf2f(p[64]);                    \
          GXP[it][2]=bf2f(p[128]); GXP[it][3]=bf2f(p[192]);                   \
        }                                                                     \
      }                                                                       \
    }                                                                         \
    f32x4 acc1_0=(f32x4)(0.f), acc1_1=(f32x4)(0.f);                           \
    f32x4 acc1_2=(f32x4)(0.f), acc1_3=(f32x4)(0.f);                           \
    f32x4 acc2=(f32x4)(0.f);                                                  \
    _Pragma("unroll")                                                         \
    for (int kw = 0; kw < 2; ++kw) {                                          \
      short8_t bfrag = *reinterpret_cast<const short8_t*>(&Hn[fr][kw*32+fk]); \
      acc1_0 = __builtin_amdgcn_mfma_f32_16x16x32_bf16(ureg[0][kw], bfrag, acc1_0,0,0,0); \
      acc1_1 = __builtin_amdgcn_mfma_f32_16x16x32_bf16(ureg[1][kw], bfrag, acc1_1,0,0,0); \
      acc1_2 = __builtin_amdgcn_mfma_f32_16x16x32_bf16(ureg[2][kw], bfrag, acc1_2,0,0,0); \
      acc1_3 = __builtin_amdgcn_mfma_f32_16x16x32_bf16(ureg[3][kw], bfrag, acc1_3,0,0,0); \
      short8_t cfrag = *reinterpret_cast<const short8_t*>(&Cn[fr][kw*32+fk]); \
      acc2 = __builtin_amdgcn_mfma_f32_16x16x32_bf16(wdreg[kw], cfrag, acc2,0,0,0); \
    }                                                                         \
    *reinterpret_cast<f32x4*>(&G1[l15][wave*64 +  0 + h4]) = acc1_0;          \
    *reinterpret_cast<f32x4*>(&G1[l15][wave*64 + 16 + h4]) = acc1_1;          \
    *reinterpret_cast<f32x4*>(&G1[l15][wave*64 + 32 + h4]) = acc1_2;          \
    *reinterpret_cast<f32x4*>(&G1[l15][wave*64 + 48 + h4]) = acc1_3;          \
    *reinterpret_cast<f32x4*>(&G2l[l15][wave*16 + h4]) = acc2;                \
    __syncthreads();                                                          \
    _Pragma("unroll")                                                         \
    for (int it = 0; it < 2; ++it) {                                          \
      int d = it*4 + wave;                                                    \
      if (d < NDY) {                                                          \
        float gf = G1[d][lane]       + GXU[it][0];                            \
        float gi = G1[d][64 + lane]  + GXU[it][1];                            \
        float go = G1[d][128 + lane] + GXU[it][2];                            \
        float gc = G1[d][192 + lane] + GXU[it][3];                            \
        float f  = sigm(gf), ig = sigm(gi), og = sigm(go), ct = sigm(gc);     \
        float cs1 = tanhfast(G2l[d][lane] + bdl[lane]);                       \
        float tvv = tsl[d][(T_CUR)];                                          \
        float c  = Cf[d][lane];                                               \
        float cadj = c - cs1 + cs1*tvv;                                       \
        float c2 = f*cadj + ig*ct;                                            \
        float h2 = og*tanhfast(c2);                                           \
        Cf[d][lane] = c2; Cn[d][lane] = f2bf(c2); Hn[d][lane] = f2bf(h2);     \
        outs_lds[d][(T_CUR)][lane] = f2bf(h2);                                \
      }                                                                       \
    }                                                                         \
    __syncthreads();                                                          \
  }

__global__ __launch_bounds__(256) void k_recur(
    const unsigned short* __restrict__ GX, const float* __restrict__ Uall,
    const float* __restrict__ Wd, const float* __restrict__ bd,
    const float* __restrict__ ts, const float* __restrict__ taW,
    const float* __restrict__ tab, float* __restrict__ news)
{
  const int bid = blockIdx.x;
  const int s  = bid / 5;
  const int d0 = (bid % 5) * NDY;
  const int tid = threadIdx.x;
  const int lane = tid & 63, wave = tid >> 6;
  const int fr = lane & 15, fk = (lane >> 4) * 8;
  const int l15 = lane & 15, h4 = (lane >> 4) * 4;

  __shared__ float G1[16][260];
  __shared__ float G2l[16][68];
  __shared__ float Cf[8][68];
  __shared__ short Hn[16][72];
  __shared__ short Cn[16][72];
  __shared__ float tsl[NDY][T_];
  __shared__ float bdl[H_], tabl[H_];
  __shared__ float scl[NDY][T_];
  __shared__ short outs_lds[NDY][T_][68];

  for (int e = tid; e < 16*72; e += 256) { (&Hn[0][0])[e] = 0; (&Cn[0][0])[e] = 0; }
  for (int e = tid; e < 8*68; e += 256) (&Cf[0][0])[e] = 0.f;
  for (int e = tid; e < NDY*T_; e += 256)
    (&tsl[0][0])[e] = ts[((size_t)s*D_ + d0)*T_ + e];
  if (tid < H_) { bdl[tid] = bd[s*H_ + tid]; tabl[tid] = tab[s*H_ + tid]; }

  short8_t ureg[4][2], wdreg[2], twreg[2];
  {
    const float* Uf  = Uall + (size_t)s*G4*H_;
    const float* Wdf = Wd   + (size_t)s*H_*H_;
    const float* Twf = taW  + (size_t)s*H_*H_;
    #pragma unroll
    for (int mt = 0; mt < 4; ++mt)
      #pragma unroll
      for (int kw = 0; kw < 2; ++kw) {
        const float* p = Uf + (size_t)(wave*64 + mt*16 + fr)*H_ + kw*32 + fk;
        ureg[mt][kw] = pack8(*reinterpret_cast<const float4*>(p),
                             *reinterpret_cast<const float4*>(p + 4));
      }
    #pragma unroll
    for (int kw = 0; kw < 2; ++kw) {
      const float* p = Wdf + (size_t)(wave*16 + fr)*H_ + kw*32 + fk;
      wdreg[kw] = pack8(*reinterpret_cast<const float4*>(p),
                        *reinterpret_cast<const float4*>(p + 4));
      const float* q = Twf + (size_t)(wave*16 + fr)*H_ + kw*32 + fk;
      twreg[kw] = pack8(*reinterpret_cast<const float4*>(q),
                        *reinterpret_cast<const float4*>(q + 4));
    }
  }
  __syncthreads();

  float gxA[2][4], gxB[2][4];
  {
    const unsigned short* GXt = GX + ((size_t)s*M_ + d0*T_)*G4;
    #pragma unroll
    for (int it = 0; it < 2; ++it) {
      int d = it*4 + wave;
      if (d < NDY) {
        const unsigned short* p = GXt + (size_t)d*T_*G4 + lane;
        gxA[it][0]=bf2f(p[0]);   gxA[it][1]=bf2f(p[64]);
        gxA[it][2]=bf2f(p[128]); gxA[it][3]=bf2f(p[192]);
      }
    }
  }

  for (int t = 0; t < T_; t += 2) {
    RECUR_STEP(t,   gxA, gxB)
    RECUR_STEP(t+1, gxB, gxA)
  }

  // ---- folded day attention ----
  {
    f32x4 accv = (f32x4)(0.f);
    #pragma unroll
    for (int kw = 0; kw < 2; ++kw) {
      short8_t hfr = *reinterpret_cast<const short8_t*>(&Hn[fr][kw*32+fk]);
      accv = __builtin_amdgcn_mfma_f32_16x16x32_bf16(twreg[kw], hfr, accv, 0,0,0);
    }
    *reinterpret_cast<f32x4*>(&G2l[l15][wave*16 + h4]) = accv;
  }
  __syncthreads();
  for (int e = tid; e < NDY*H_; e += 256) {
    int d = e >> 6, i = e & 63;
    G2l[d][i] += tabl[i];
  }
  __syncthreads();
  for (int idx = tid; idx < NDY*T_; idx += 256) {
    int d = idx / T_, t = idx % T_;
    float sc = 0.f;
    #pragma unroll 8
    for (int l = 0; l < H_; ++l)
      sc = fmaf(bf2f((unsigned short)outs_lds[d][t][l]), G2l[d][l], sc);
    scl[d][t] = sc;
  }
  __syncthreads();
  if (tid < NDY) {
    float m = -1e30f;
    for (int t = 0; t < T_; ++t) m = fmaxf(m, scl[tid][t]);
    float sum = 0.f;
    for (int t = 0; t < T_; ++t) { float e = __expf(scl[tid][t]-m); scl[tid][t]=e; sum+=e; }
    float inv = 1.f/sum;
    for (int t = 0; t < T_; ++t) scl[tid][t] *= inv;
  }
  __syncthreads();
  {
    const int l = tid & 63, w = tid >> 6;
    for (int d = w; d < NDY; d += 4) {
      float o = 0.f;
      #pragma unroll 8
      for (int t = 0; t < T_; ++t)
        o = fmaf(scl[d][t], bf2f((unsigned short)outs_lds[d][t][l]), o);
      news[((size_t)s*D_ + d0 + d)*H_ + l] = o;
    }
  }
}

// ---------------------------------------------------------------- K4: stock-GRU over news + attention -> tvec
__global__ __launch_bounds__(256) void k_rnn(
    const float* __restrict__ news, const float* __restrict__ sWih,
    const float* __restrict__ sWhh, const float* __restrict__ sbih,
    const float* __restrict__ sbhh, const float* __restrict__ saW,
    const float* __restrict__ sab, float* __restrict__ tvecg)
{
  const int s = blockIdx.x;
  const int tid = threadIdx.x;
  const int row = tid & 63, q = tid >> 6;
  __shared__ float xs[H_], hs[H_];
  __shared__ float outsb[D_][H_+1];
  __shared__ float gsum[128], gxn[64], ghn[64];
  __shared__ float pt[4][H_], vs[H_], as_[D_];

  float wih[64]; float whh[64]; float bihr=0.f, bhhr=0.f;
  if (tid < G3) {
    const float* wp = sWih + ((size_t)s*G3 + tid)*H_;
    const float* hp = sWhh + ((size_t)s*G3 + tid)*H_;
    #pragma unroll
    for (int j=0;j<64;++j) { wih[j]=wp[j]; whh[j]=hp[j]; }
    bihr = sbih[s*G3+tid]; bhhr = sbhh[s*G3+tid];
  }
  if (tid < H_) hs[tid]=0.f;
  __syncthreads();

  for (int d=0; d<D_; ++d) {
    if (tid < H_) xs[tid] = news[((size_t)s*D_ + d)*H_ + tid];
    __syncthreads();
    if (tid < G3) {
      float gx = bihr, gh = bhhr;
      const float4* x4 = reinterpret_cast<const float4*>(xs);
      const float4* h4p = reinterpret_cast<const float4*>(hs);
      #pragma unroll
      for (int j4=0;j4<16;++j4) {
        float4 xv=x4[j4]; float4 hv=h4p[j4];
        gx = fmaf(wih[j4*4+0],xv.x,gx); gx = fmaf(wih[j4*4+1],xv.y,gx);
        gx = fmaf(wih[j4*4+2],xv.z,gx); gx = fmaf(wih[j4*4+3],xv.w,gx);
        gh = fmaf(whh[j4*4+0],hv.x,gh); gh = fmaf(whh[j4*4+1],hv.y,gh);
        gh = fmaf(whh[j4*4+2],hv.z,gh); gh = fmaf(whh[j4*4+3],hv.w,gh);
      }
      if (tid < 128) gsum[tid] = gx + gh;
      else { gxn[tid-128] = gx; ghn[tid-128] = gh; }
    }
    __syncthreads();
    if (tid < H_) {
      float r = sigm(gsum[tid]);
      float z = sigm(gsum[64+tid]);
      float n = tanhf(gxn[tid] + r*ghn[tid]);
      float h2 = (1.f-z)*n + z*hs[tid];
      hs[tid]=h2; outsb[d][tid]=h2;
    }
    __syncthreads();
  }

  {
    const float* Wp = saW + ((size_t)s*H_ + row)*H_ + q*16;
    float p = 0.f;
    #pragma unroll
    for (int j=0;j<16;++j) p = fmaf(Wp[j], hs[q*16+j], p);
    pt[q][row] = p;
    __syncthreads();
    if (tid < H_) vs[tid] = pt[0][tid]+pt[1][tid]+pt[2][tid]+pt[3][tid] + sab[s*H_+tid];
    __syncthreads();
    if (tid < D_) {
      float sc = 0.f;
      for (int h=0;h<H_;++h) sc = fmaf(outsb[tid][h], vs[h], sc);
      as_[tid] = sc;
    }
    __syncthreads();
    if (tid == 0) {
      float m = -1e30f;
      for (int t=0;t<D_;++t) m = fmaxf(m, as_[t]);
      float sum = 0.f;
      for (int t=0;t<D_;++t) { float e = __expf(as_[t]-m); as_[t]=e; sum += e; }
      float inv = 1.0f/sum;
      for (int t=0;t<D_;++t) as_[t] *= inv;
    }
    __syncthreads();
    if (tid < H_) {
      float acc = 0.f;
      for (int t=0;t<D_;++t) acc = fmaf(as_[t], outsb[t][tid], acc);
      tvecg[s*H_+tid] = acc;
    }
  }
}

// ---------------------------------------------------------------- K5b: bilinear -> feat
__global__ __launch_bounds__(256) void k_bilin(
    const float* __restrict__ tvec, const float* __restrict__ xvec,
    const float* __restrict__ biW, const float* __restrict__ bib,
    float* __restrict__ feat)
{
  const int s = blockIdx.x >> 2;
  const int k0 = (blockIdx.x & 3) * 16;
  const int tid = threadIdx.x;
  const int lane = tid & 63, w = tid >> 6;
  __shared__ float pmat[H_*H_];
  __shared__ float tl[H_], xl[H_];
  if (tid < H_) { tl[tid] = tvec[s*H_+tid]; xl[tid] = xvec[s*H_+tid]; }
  __syncthreads();
  for (int e = tid; e < H_*H_; e += 256) pmat[e] = tl[e>>6]*xl[e&63];
  __syncthreads();
  const float4* P4 = reinterpret_cast<const float4*>(pmat);
  #pragma unroll
  for (int kk = 0; kk < 4; ++kk) {
    int k = k0 + kk*4 + w;
    const float4* W4 = reinterpret_cast<const float4*>(biW + ((size_t)s*H_ + k)*H_*H_);
    float acc = 0.f;
    #pragma unroll
    for (int r = 0; r < 16; ++r) {
      float4 wv = W4[r*64 + lane];
      float4 pv = P4[r*64 + lane];
      acc += wv.x*pv.x + wv.y*pv.y + wv.z*pv.z + wv.w*pv.w;
    }
    #pragma unroll
    for (int off = 32; off > 0; off >>= 1) acc += __shfl_down(acc, off, 64);
    if (lane == 0) feat[s*H_ + k] = tanhf(acc + bib[s*H_+k]);
  }
}

// ---------------------------------------------------------------- K6a: Q,K projections (100 blocks)
__global__ __launch_bounds__(128) void k_qk(
    const float* __restrict__ feat, const float* __restrict__ Wq,
    const float* __restrict__ bq, const float* __restrict__ Wk,
    const float* __restrict__ bk, float* __restrict__ Qg,
    float* __restrict__ Kg)
{
  const int s = blockIdx.x;
  const int tid = threadIdx.x;
  __shared__ float fsl[H_];
  if (tid < H_) fsl[tid] = feat[s*H_ + tid];
  __syncthreads();
  const int o = tid & 63;
  const int which = tid >> 6;             // 0 = Q, 1 = K
  const float* W = which ? Wk : Wq;
  float a = which ? bk[o] : bq[o];
  const float* wr = W + o*H_;
  #pragma unroll 8
  for (int h = 0; h < H_; ++h) a = fmaf(fsl[h], wr[h], a);
  (which ? Kg : Qg)[s*H_ + o] = a;
}

// ---------------------------------------------------------------- K6b: per-stock MHA + fc + out + loss term (100 blocks)
__global__ __launch_bounds__(256) void k_attn(
    const float* __restrict__ feat, const float* __restrict__ Qg,
    const float* __restrict__ Kg, const float* __restrict__ blW,
    const float* __restrict__ blb, const float* __restrict__ fcW,
    const float* __restrict__ fcb, const int* __restrict__ label,
    float* __restrict__ lt, float* __restrict__ dout)
{
  const int s = blockIdx.x;
  const int tid = threadIdx.x;
  __shared__ float Kl[S_][H_];
  __shared__ float Vl[S_][H_];
  __shared__ float ql[H_], mhl[H_], o1l[2];
  __shared__ float scl[4][S_];

  for (int e = tid; e < S_*H_; e += 256) {
    Kl[e>>6][e&63] = Kg[e];
    Vl[e>>6][e&63] = feat[e];
  }
  if (tid < H_) ql[tid] = Qg[s*H_ + tid];
  __syncthreads();

  for (int idx = tid; idx < 4*S_; idx += 256) {
    const int hd = idx / S_, t = idx - hd*S_;
    float sc = 0.f;
    #pragma unroll
    for (int d2 = 0; d2 < 16; ++d2)
      sc = fmaf(ql[hd*16 + d2], Kl[t][hd*16 + d2], sc);
    scl[hd][t] = sc * 0.25f;
  }
  __syncthreads();
  if (tid < 4) {
    float m = -1e30f;
    for (int t = 0; t < S_; ++t) m = fmaxf(m, scl[tid][t]);
    float sum = 0.f;
    for (int t = 0; t < S_; ++t) { float e = __expf(scl[tid][t]-m); scl[tid][t]=e; sum+=e; }
    float inv = 1.f/sum;
    for (int t = 0; t < S_; ++t) scl[tid][t] *= inv;
  }
  if (tid >= 64 && tid < 66) {
    const int c = tid - 64;
    const float* w = blW + ((size_t)(S_-1)*2 + c)*H_;
    float a = blb[(S_-1)*2 + c];
    #pragma unroll 8
    for (int h = 0; h < H_; ++h) a = fmaf(Vl[s][h], w[h], a);
    o1l[c] = tanhf(a);
  }
  __syncthreads();
  if (tid < H_) {
    const int hd = tid >> 4;
    float a = 0.f;
    #pragma unroll 4
    for (int t = 0; t < S_; ++t) a = fmaf(scl[hd][t], Vl[t][tid], a);
    mhl[tid] = a;
  }
  __syncthreads();
  if (tid == 0) {
    float e0 = fcb[0], e1 = fcb[1];
    for (int h = 0; h < H_; ++h) {
      float mv = mhl[h];
      e0 = fmaf(mv, fcW[h], e0);
      e1 = fmaf(mv, fcW[H_ + h], e1);
    }
    float x0 = e0 > 0.f ? e0 : (__expf(e0) - 1.f);
    float x1 = e1 > 0.f ? e1 : (__expf(e1) - 1.f);
    float y0 = x0 + o1l[0], y1 = x1 + o1l[1];
    float mm = fmaxf(y0, y1);
    float p0 = __expf(y0 - mm), p1 = __expf(y1 - mm);
    float is = 1.f / (p0 + p1);
    float out0 = p0 * is, out1 = p1 * is;
    float m2 = fmaxf(out0, out1);
    float lse = m2 + logf(__expf(out0 - m2) + __expf(out1 - m2));
    float ol = (label[s] != 0) ? out1 : out0;
    lt[s] = lse - ol;
    dout[1 + s*2] = out0;
    dout[2 + s*2] = out1;
  }
}

// ---------------------------------------------------------------- K6c: loss reduce
__global__ __launch_bounds__(128) void k_loss(
    const float* __restrict__ lt, float* __restrict__ dout)
{
  const int tid = threadIdx.x;
  __shared__ float buf[128];
  buf[tid] = (tid < S_) ? lt[tid] : 0.f;
  __syncthreads();
  #pragma unroll
  for (int off = 64; off > 0; off >>= 1) {
    if (tid < off) buf[tid] += buf[tid + off];
    __syncthreads();
  }
  if (tid == 0) dout[0] = buf[0] * (1.0f / (float)S_);
}

// ---------------------------------------------------------------- launch
extern "C" void kernel_launch(void* const* d_in, const int* in_sizes, int n_in,
                              void* d_out, int out_size, void* d_ws, size_t ws_size,
                              hipStream_t stream) {
  const float* pg_Wih  = (const float*)d_in[0];
  const float* pg_Whh  = (const float*)d_in[1];
  const float* pg_bih  = (const float*)d_in[2];
  const float* pg_bhh  = (const float*)d_in[3];
  const float* pa_W    = (const float*)d_in[4];
  const float* pa_b    = (const float*)d_in[5];
  const float* tl_Wall = (const float*)d_in[6];
  const float* tl_bWall= (const float*)d_in[7];
  const float* tl_Uall = (const float*)d_in[8];
  const float* tl_bUall= (const float*)d_in[9];
  const float* tl_Wd   = (const float*)d_in[10];
  const float* tl_bd   = (const float*)d_in[11];
  const float* ta_W    = (const float*)d_in[12];
  const float* ta_b    = (const float*)d_in[13];
  const float* sg_Wih  = (const float*)d_in[14];
  const float* sg_Whh  = (const float*)d_in[15];
  const float* sg_bih  = (const float*)d_in[16];
  const float* sg_bhh  = (const float*)d_in[17];
  const float* sa_W    = (const float*)d_in[18];
  const float* sa_b    = (const float*)d_in[19];
  const float* bi_W    = (const float*)d_in[20];
  const float* bi_b    = (const float*)d_in[21];
  const float* bl_W    = (const float*)d_in[22];
  const float* bl_b    = (const float*)d_in[23];
  const float* mha_Wq  = (const float*)d_in[24];
  const float* mha_bq  = (const float*)d_in[25];
  const float* mha_Wk  = (const float*)d_in[26];
  const float* mha_bk  = (const float*)d_in[27];
  const float* fc_W    = (const float*)d_in[28];
  const float* fc_b    = (const float*)d_in[29];
  const float* text    = (const float*)d_in[30];
  const float* price   = (const float*)d_in[31];
  const float* tstamps = (const float*)d_in[32];
  const int*   label   = (const int*)d_in[33];
  (void)in_sizes; (void)n_in; (void)out_size; (void)ws_size;

  // workspace layout
  unsigned short* GXbf = (unsigned short*)d_ws;               // 30,720,000 us
  float* news   = (float*)(GXbf + (size_t)S_*M_*G4);          // 192,000 f
  float* xvec   = news + (size_t)S_*D_*H_;                    // 6,400 f
  float* feat   = xvec + (size_t)S_*H_;                       // 6,400 f
  float* Qg     = feat + (size_t)S_*H_;                       // 6,400 f
  float* Kg     = Qg   + (size_t)S_*H_;                       // 6,400 f
  float* ltb    = Kg   + (size_t)S_*H_;                       // 100 f
  float* tvecg  = ltb  + 128;                                 // 6,400 f
  float* dout   = (float*)d_out;

  k_gemm_price<<<1100, 512, 0, stream>>>(text, tl_Wall, tl_bWall, tl_bUall, GXbf,
                                         price, pg_Wih, pg_Whh, pg_bih, pg_bhh,
                                         pa_W, pa_b, xvec);
  k_recur<<<5*S_, 256, 0, stream>>>(GXbf, tl_Uall, tl_Wd, tl_bd, tstamps, ta_W, ta_b, news);
  k_rnn<<<S_, 256, 0, stream>>>(news, sg_Wih, sg_Whh, sg_bih, sg_bhh, sa_W, sa_b, tvecg);
  k_bilin<<<4*S_, 256, 0, stream>>>(tvecg, xvec, bi_W, bi_b, feat);
  k_qk<<<S_, 128, 0, stream>>>(feat, mha_Wq, mha_bq, mha_Wk, mha_bk, Qg, Kg);
  k_attn<<<S_, 256, 0, stream>>>(feat, Qg, Kg, bl_W, bl_b, fc_W, fc_b, label, ltb, dout);
  k_loss<<<1, 128, 0, stream>>>(ltb, dout);
}